// Round 2
// 310.096 us; speedup vs baseline: 1.0120x; 1.0120x over previous
//
#include <hip/hip_runtime.h>

#define B_ 16
#define S_ 1024
#define E_ 512
#define H_ 8
#define D_ 64
#define L_ 4
#define M_ (B_*S_)   // 16384 tokens

typedef unsigned short u16;
typedef __attribute__((ext_vector_type(8))) short bf16x8;  // 8 bf16 = 4 VGPRs
typedef __attribute__((ext_vector_type(4))) float f32x4;
typedef __attribute__((ext_vector_type(4))) unsigned uint4v;

__device__ __forceinline__ u16 f2bf(float x) {
  unsigned u = __float_as_uint(x);
  unsigned r = (u + 0x7fffu + ((u >> 16) & 1u)) >> 16;  // RNE
  return (u16)r;
}
__device__ __forceinline__ ushort4 f2bf4(float4 f) {
  ushort4 u;
  u.x = f2bf(f.x); u.y = f2bf(f.y); u.z = f2bf(f.z); u.w = f2bf(f.w);
  return u;
}
// single-instruction pack: two f32 -> packed bf16x2 (lo in low half)
__device__ __forceinline__ unsigned cvt_pk_bf16(float lo, float hi) {
  unsigned r;
  asm("v_cvt_pk_bf16_f32 %0, %1, %2" : "=v"(r) : "v"(lo), "v"(hi));
  return r;
}

typedef __attribute__((address_space(1))) const void gconst_void;
typedef __attribute__((address_space(3))) void lds_void;
__device__ __forceinline__ void gl_lds16(const void* g, void* l) {
  // async global->LDS, 16B per lane; LDS dest = wave-uniform base + lane*16
  __builtin_amdgcn_global_load_lds((gconst_void*)g, (lds_void*)l, 16, 0, 0);
}

// ---------------- fused weight prep (all 4 weight matrices + biases) ----------------
__global__ __launch_bounds__(256) void prep_w(
    const float* __restrict__ Wq, const float* __restrict__ Wk,
    const float* __restrict__ Wv_sh, const float* __restrict__ Wv_sp,
    const float* __restrict__ Wo_sh, const float* __restrict__ Wo_sp,
    const float* __restrict__ bv_sh, const float* __restrict__ bv_sp,
    const float* __restrict__ bo_sh, const float* __restrict__ bo_sp,
    const int* __restrict__ langp,
    u16* __restrict__ Wq_b, u16* __restrict__ Wk_b,
    u16* __restrict__ Wv_b, u16* __restrict__ Wo_b,
    float* __restrict__ bv_f, float* __restrict__ bo_f) {
  int lang = langp[0];
  int i = blockIdx.x * 256 + threadIdx.x;           // over E_*E_/4
  size_t wofs = (size_t)lang * (E_*E_/4) + i;
  ((ushort4*)Wq_b)[i] = f2bf4(((const float4*)Wq)[i]);
  ((ushort4*)Wk_b)[i] = f2bf4(((const float4*)Wk)[i]);
  float4 vs = ((const float4*)Wv_sh)[i], vp = ((const float4*)Wv_sp)[wofs];
  float4 os = ((const float4*)Wo_sh)[i], op = ((const float4*)Wo_sp)[wofs];
  float4 vv = {vs.x*vp.x, vs.y*vp.y, vs.z*vp.z, vs.w*vp.w};
  float4 oo = {os.x*op.x, os.y*op.y, os.z*op.z, os.w*op.w};
  ((ushort4*)Wv_b)[i] = f2bf4(vv);
  ((ushort4*)Wo_b)[i] = f2bf4(oo);
  if (i < E_/4) {
    float4 b1 = ((const float4*)bv_sh)[i], b2 = ((const float4*)(bv_sp + (size_t)lang*E_))[i];
    float4 b3 = ((const float4*)bo_sh)[i], b4 = ((const float4*)(bo_sp + (size_t)lang*E_))[i];
    float4 r1 = {b1.x+b2.x, b1.y+b2.y, b1.z+b2.z, b1.w+b2.w};
    float4 r2 = {b3.x+b4.x, b3.y+b4.y, b3.z+b4.z, b3.w+b4.w};
    ((float4*)bv_f)[i] = r1;
    ((float4*)bo_f)[i] = r2;
  }
}

// ---------------- fused QKV projection GEMM: {Q,K,V}b = {q,k,v} @ W^T + b ----------------
// blockIdx.y selects matrix. A fp32 staged via global_load_lds (16B = 4 floats),
// converted to bf16 on the LDS->fragment read. 128x128 tile, BK=32, 4 waves 2x2.
// XCD-swizzled 1D grid: 512 work items, chunk=64/XCD -> A-panels L2-resident.
__global__ __launch_bounds__(256) void gemm_qkv(
    const float* __restrict__ q, const float* __restrict__ k, const float* __restrict__ v,
    const u16* __restrict__ Wq_b, const u16* __restrict__ Wk_b, const u16* __restrict__ Wv_b,
    const float* __restrict__ bq, const float* __restrict__ bk, const float* __restrict__ bv,
    u16* __restrict__ Qb, u16* __restrict__ Kb, u16* __restrict__ Vb) {
  __shared__ __align__(16) float sAf[128*32];
  __shared__ __align__(16) u16 sB[128*32];
  const int z = blockIdx.y;
  const float* A    = (z == 0) ? q : (z == 1) ? k : v;
  const u16*   Bw   = (z == 0) ? Wq_b : (z == 1) ? Wk_b : Wv_b;
  const float* bias = (z == 0) ? bq : (z == 1) ? bk : bv;
  u16*         out  = (z == 0) ? Qb : (z == 1) ? Kb : Vb;
  const int t = threadIdx.x;
  // XCD swizzle: 512 blocks, 8 XCDs, 64/chunk (512%8==0 -> bijective)
  const int hw = blockIdx.x;
  const int wk = (hw & 7) * 64 + (hw >> 3);
  const int m0 = (wk >> 2) * 128, n0 = (wk & 3) * 128;
  const int lane = t & 63, wid = t >> 6;
  const int m16 = lane & 15, qq = lane >> 4;
  const int wrow = (wid >> 1) * 64, wcol = (wid & 1) * 64;
  f32x4 acc[4][4] = {};
  // A staging: chunk ca = 1KB = 8 rows x 32 floats; lane l -> row ca*8+(l>>3), col (l&7)*4
  const int ca0 = wid*4;
  const float* ap[4];
  float* sap[4];
#pragma unroll
  for (int i = 0; i < 4; ++i) {
    int ca = ca0 + i;
    ap[i]  = A + (size_t)(m0 + ca*8 + (lane >> 3)) * E_ + (lane & 7) * 4;
    sap[i] = &sAf[ca * 256];
  }
  // B staging: chunk cb = 512 u16 = 16 rows x 32; lane l -> row cb*16+(l>>2), col 8*(l&3)
  const int cb0 = wid*2, cb1 = wid*2 + 1;
  const u16* bp0 = Bw + (size_t)(n0 + cb0*16 + (lane >> 2)) * E_ + (lane & 3) * 8;
  const u16* bp1 = Bw + (size_t)(n0 + cb1*16 + (lane >> 2)) * E_ + (lane & 3) * 8;
  u16* sbp0 = &sB[cb0 * 512];
  u16* sbp1 = &sB[cb1 * 512];
  for (int k0 = 0; k0 < E_; k0 += 32) {
#pragma unroll
    for (int i = 0; i < 4; ++i) gl_lds16(ap[i], sap[i]);
    gl_lds16(bp0, sbp0);
    gl_lds16(bp1, sbp1);
    __syncthreads();   // drains vmcnt -> LDS data visible
    bf16x8 af[4], bfm[4];
#pragma unroll
    for (int mt = 0; mt < 4; ++mt) {
      const float* ar = &sAf[(wrow + mt*16 + m16) * 32 + qq*8];
      f32x4 a0 = *(const f32x4*)ar;
      f32x4 a1 = *(const f32x4*)(ar + 4);
      union { uint4v u; bf16x8 h; } cv;
      cv.u = (uint4v){ cvt_pk_bf16(a0[0], a0[1]), cvt_pk_bf16(a0[2], a0[3]),
                       cvt_pk_bf16(a1[0], a1[1]), cvt_pk_bf16(a1[2], a1[3]) };
      af[mt] = cv.h;
    }
#pragma unroll
    for (int nt = 0; nt < 4; ++nt)
      bfm[nt] = *(const bf16x8*)&sB[(wcol + nt*16 + m16) * 32 + qq*8];
#pragma unroll
    for (int mt = 0; mt < 4; ++mt)
#pragma unroll
      for (int nt = 0; nt < 4; ++nt)
        acc[mt][nt] = __builtin_amdgcn_mfma_f32_16x16x32_bf16(af[mt], bfm[nt], acc[mt][nt], 0, 0, 0);
    __syncthreads();
#pragma unroll
    for (int i = 0; i < 4; ++i) ap[i] += 32;
    bp0 += 32; bp1 += 32;
  }
  float bvv[4];
#pragma unroll
  for (int nt = 0; nt < 4; ++nt) bvv[nt] = bias[n0 + wcol + nt*16 + m16];
#pragma unroll
  for (int mt = 0; mt < 4; ++mt) {
    int gm = m0 + wrow + mt*16 + qq*4;   // C/D: row = quad*4 + reg
#pragma unroll
    for (int nt = 0; nt < 4; ++nt) {
      int gn = n0 + wcol + nt*16 + m16;  // C/D: col = lane&15
#pragma unroll
      for (int r = 0; r < 4; ++r)
        out[(size_t)(gm + r) * E_ + gn] = f2bf(acc[mt][nt][r] + bvv[nt]);
    }
  }
}

// ---------------- bf16 MFMA GEMM (m97 structure): Y = A @ Bw^T + bias, fp32 out ----------------
__global__ __launch_bounds__(256) void gemm_lds(
    const u16* __restrict__ A, const u16* __restrict__ Bw,
    const float* __restrict__ bias, float* __restrict__ out) {
  __shared__ __align__(16) u16 sA[128*32];
  __shared__ __align__(16) u16 sB[128*32];
  const int t = threadIdx.x;
  // XCD swizzle: 512 blocks, chunk=64/XCD
  const int hw = blockIdx.x;
  const int wk = (hw & 7) * 64 + (hw >> 3);
  const int m0 = (wk >> 2) * 128, n0 = (wk & 3) * 128;
  const int lane = t & 63, wid = t >> 6;
  const int m16 = lane & 15, qq = lane >> 4;
  const int wrow = (wid >> 1) * 64, wcol = (wid & 1) * 64;
  f32x4 acc[4][4] = {};
  const int c0 = 2*wid, c1 = 2*wid + 1;
  const int colk = (lane & 3) * 8;
  const int r0 = c0*16 + (lane >> 2), r1 = c1*16 + (lane >> 2);
  const u16* a0 = A  + (size_t)(m0 + r0) * E_ + colk;
  const u16* a1 = A  + (size_t)(m0 + r1) * E_ + colk;
  const u16* b0 = Bw + (size_t)(n0 + r0) * E_ + colk;
  const u16* b1 = Bw + (size_t)(n0 + r1) * E_ + colk;
  u16* sa0 = &sA[c0*512]; u16* sa1 = &sA[c1*512];
  u16* sb0 = &sB[c0*512]; u16* sb1 = &sB[c1*512];
  for (int k0 = 0; k0 < E_; k0 += 32) {
    gl_lds16(a0, sa0);
    gl_lds16(a1, sa1);
    gl_lds16(b0, sb0);
    gl_lds16(b1, sb1);
    __syncthreads();
    bf16x8 af[4], bfm[4];
#pragma unroll
    for (int mt = 0; mt < 4; ++mt)
      af[mt] = *(const bf16x8*)&sA[(wrow + mt*16 + m16) * 32 + qq*8];
#pragma unroll
    for (int nt = 0; nt < 4; ++nt)
      bfm[nt] = *(const bf16x8*)&sB[(wcol + nt*16 + m16) * 32 + qq*8];
#pragma unroll
    for (int mt = 0; mt < 4; ++mt)
#pragma unroll
      for (int nt = 0; nt < 4; ++nt)
        acc[mt][nt] = __builtin_amdgcn_mfma_f32_16x16x32_bf16(af[mt], bfm[nt], acc[mt][nt], 0, 0, 0);
    __syncthreads();
    a0 += 32; a1 += 32; b0 += 32; b1 += 32;
  }
  float bv[4];
#pragma unroll
  for (int nt = 0; nt < 4; ++nt) bv[nt] = bias[n0 + wcol + nt*16 + m16];
#pragma unroll
  for (int mt = 0; mt < 4; ++mt) {
    int gm = m0 + wrow + mt*16 + qq*4;
#pragma unroll
    for (int nt = 0; nt < 4; ++nt) {
      int gn = n0 + wcol + nt*16 + m16;
#pragma unroll
      for (int r = 0; r < 4; ++r)
        out[(size_t)(gm + r) * E_ + gn] = acc[mt][nt][r] + bv[nt];
    }
  }
}

// ---------------- V transpose: Vb (M x E, token-major) -> Vt[(b,h,d)][s] ----------------
#define TS_ 72
__global__ __launch_bounds__(256) void transpose_v(const u16* __restrict__ Vb,
                                                   u16* __restrict__ Vt) {
  __shared__ __align__(16) u16 sT[64*TS_];
  const int t = threadIdx.x;
  const int bh = blockIdx.y, b = bh >> 3, h = bh & 7;
  const int s0 = blockIdx.x * 64;
  const int row = t >> 2, c0 = (t & 3) * 16;
  const u16* src = Vb + (size_t)(b*S_ + s0 + row) * E_ + h*D_ + c0;
  *(uint4*)&sT[row*TS_ + c0]     = *(const uint4*)src;
  *(uint4*)&sT[row*TS_ + c0 + 8] = *(const uint4*)(src + 8);
  __syncthreads();
  const int d = t >> 2, sc = (t & 3) * 16;
  unsigned w[8];
#pragma unroll
  for (int i = 0; i < 8; ++i) {
    unsigned lo = sT[(sc + 2*i    ) * TS_ + d];
    unsigned hi = sT[(sc + 2*i + 1) * TS_ + d];
    w[i] = lo | (hi << 16);
  }
  u16* dst = Vt + ((size_t)(b*H_ + h) * D_ + d) * S_ + s0 + sc;
  uint4 p0 = {w[0], w[1], w[2], w[3]}, p1 = {w[4], w[5], w[6], w[7]};
  *(uint4*)dst = p0;
  *(uint4*)(dst + 8) = p1;
}

// ---------------- MFMA flash attention (S^T operand order) ----------------
// Block = (b,h, 64 q-rows); 4 waves, wave w owns q-rows [w*16, w*16+16).
// QK^T computed as S^T = mfma(K, Q): C/D col=lane&15=qrow, row=quad*4+reg=key.
// -> each lane holds 4 CONSECUTIVE keys of one q-row: P written as packed b64.
// Fixed-shift softmax (scores bounded, masked -> exp2(-1e9)=0); l deferred.
// XCD-swizzled 1D grid (2048): all 16 q-blocks of a (b,h) + 16 consecutive bh
// (4MB of K/V = one L2) land on the same XCD.
#define KST 72   // padded LDS row stride (u16)
__global__ __launch_bounds__(256) void attn_mfma(
    const u16* __restrict__ Qb, const u16* __restrict__ Kb, const u16* __restrict__ Vt,
    const int* __restrict__ mask, u16* __restrict__ ctxb) {
  __shared__ __align__(16) u16 sK[64*KST];
  __shared__ __align__(16) u16 sV[64*KST];   // V^T tile: row=dim, col=key
  __shared__ __align__(16) u16 sP[64*KST];   // P tile (also final O staging)
  __shared__ __align__(16) float sMask[64];
  __shared__ __align__(16) float sL[64];
  const int t = threadIdx.x;
  const int lane = t & 63, w = t >> 6;
  const int m16 = lane & 15, quad = lane >> 4;
  // XCD swizzle: 2048 blocks, 8 XCDs, 256/chunk (bijective)
  const int hw = blockIdx.x;
  const int wk = (hw & 7) * 256 + (hw >> 3);
  const int bh = wk >> 4, b = bh >> 3, h = bh & 7;
  const int qblk = (wk & 15) * 64;
  const int q0 = qblk + w * 16;
  bf16x8 qf0, qf1;   // B-operand layout: n=lane&15=qrow, k=quad*8+j; two k-steps over D=64
  {
    const u16* qp = Qb + (size_t)(b*S_ + q0 + m16) * E_ + h*D_ + quad*8;
    qf0 = *(const bf16x8*)qp;
    qf1 = *(const bf16x8*)(qp + 32);
  }
  f32x4 oacc[4] = {};
  float lpart = 0.f;
  const int srow = t >> 2, sc0 = (t & 3) * 16;
  const u16* kp = Kb + (size_t)(b*S_ + srow) * E_ + h*D_ + sc0;
  const u16* vp = Vt + ((size_t)(b*H_ + h) * D_ + srow) * S_ + sc0;
  // preload tile 0 into registers
  uint4 rk0 = *(const uint4*)kp, rk1 = *(const uint4*)(kp + 8);
  uint4 rv0 = *(const uint4*)vp, rv1 = *(const uint4*)(vp + 8);
  float rmsk = 0.f;
  if (t < 64) rmsk = (mask[b*S_ + t] == 0) ? -1e9f : 0.f;
  const float CS = 0.015625f * 1.44269504f;   // (1/64)*log2(e)
  for (int kt = 0; kt < S_; kt += 64) {
    *(uint4*)&sK[srow*KST + sc0]     = rk0;
    *(uint4*)&sK[srow*KST + sc0 + 8] = rk1;
    *(uint4*)&sV[srow*KST + sc0]     = rv0;
    *(uint4*)&sV[srow*KST + sc0 + 8] = rv1;
    if (t < 64) sMask[t] = rmsk;
    __syncthreads();
    // prefetch next tile (latency hidden behind this tile's compute)
    if (kt + 64 < S_) {
      kp += (size_t)64 * E_; vp += 64;
      rk0 = *(const uint4*)kp; rk1 = *(const uint4*)(kp + 8);
      rv0 = *(const uint4*)vp; rv1 = *(const uint4*)(vp + 8);
      if (t < 64) rmsk = (mask[b*S_ + kt + 64 + t] == 0) ? -1e9f : 0.f;
    }
    // ---- S^T = K Q^T : A=K (m=key), B=Q (n=qrow); 4 key-tiles x 2 k-steps ----
    f32x4 sacc[4] = {};
#pragma unroll
    for (int ct = 0; ct < 4; ++ct) {
      bf16x8 kf0 = *(const bf16x8*)&sK[(ct*16 + m16)*KST + quad*8];
      bf16x8 kf1 = *(const bf16x8*)&sK[(ct*16 + m16)*KST + 32 + quad*8];
      sacc[ct] = __builtin_amdgcn_mfma_f32_16x16x32_bf16(kf0, qf0, sacc[ct], 0, 0, 0);
      sacc[ct] = __builtin_amdgcn_mfma_f32_16x16x32_bf16(kf1, qf1, sacc[ct], 0, 0, 0);
    }
    // ---- softmax: lane has keys ct*16+quad*4+r for q-row m16 ----
#pragma unroll
    for (int ct = 0; ct < 4; ++ct) {
      f32x4 msk = *(const f32x4*)&sMask[ct*16 + quad*4];
      float p0 = exp2f(fmaf(sacc[ct][0], CS, msk[0]));
      float p1 = exp2f(fmaf(sacc[ct][1], CS, msk[1]));
      float p2 = exp2f(fmaf(sacc[ct][2], CS, msk[2]));
      float p3 = exp2f(fmaf(sacc[ct][3], CS, msk[3]));
      lpart += (p0 + p1) + (p2 + p3);
      uint2 pq = { cvt_pk_bf16(p0, p1), cvt_pk_bf16(p2, p3) };
      *(uint2*)&sP[(w*16 + m16)*KST + ct*16 + quad*4] = pq;  // A-layout, b64, wave-private
    }
    bf16x8 pf0 = *(const bf16x8*)&sP[(w*16 + m16)*KST + quad*8];
    bf16x8 pf1 = *(const bf16x8*)&sP[(w*16 + m16)*KST + 32 + quad*8];
    // ---- O += P V : A=P (m=qrow), B=V^T (n=dim); 4 dim-tiles x 2 k-steps ----
#pragma unroll
    for (int dt = 0; dt < 4; ++dt) {
      bf16x8 vf0 = *(const bf16x8*)&sV[(dt*16 + m16)*KST + quad*8];
      bf16x8 vf1 = *(const bf16x8*)&sV[(dt*16 + m16)*KST + 32 + quad*8];
      oacc[dt] = __builtin_amdgcn_mfma_f32_16x16x32_bf16(pf0, vf0, oacc[dt], 0, 0, 0);
      oacc[dt] = __builtin_amdgcn_mfma_f32_16x16x32_bf16(pf1, vf1, oacc[dt], 0, 0, 0);
    }
    __syncthreads();   // all waves done reading sK/sV before next staging
  }
  // ---- deferred l reduction: sum quad groups (lane's lpart is for qrow=m16) ----
  lpart += __shfl_xor(lpart, 16);
  lpart += __shfl_xor(lpart, 32);
  if (quad == 0) sL[w*16 + m16] = lpart;     // wave-private broadcast buffer
  // oacc C-layout: row(qrow)=quad*4+r, col(dim)=dt*16+m16 -> need l for quad*4+r
  float inv[4];
#pragma unroll
  for (int r = 0; r < 4; ++r) inv[r] = 1.0f / sL[w*16 + quad*4 + r];
  // ---- epilogue: normalize, stage in sP (wave-private rows), coalesced store ----
#pragma unroll
  for (int dt = 0; dt < 4; ++dt)
#pragma unroll
    for (int r = 0; r < 4; ++r)
      sP[(w*16 + quad*4 + r)*KST + dt*16 + m16] = f2bf(oacc[dt][r] * inv[r]);
  __syncthreads();
  const int orow = t >> 2, oc0 = (t & 3) * 16;
  uint4 o0 = *(uint4*)&sP[orow*KST + oc0];
  uint4 o1 = *(uint4*)&sP[orow*KST + oc0 + 8];
  u16* dst = ctxb + (size_t)(b*S_ + qblk + orow) * E_ + h*D_ + oc0;
  *(uint4*)dst = o0;
  *(uint4*)(dst + 8) = o1;
}

// ---------------- launch ----------------
extern "C" void kernel_launch(void* const* d_in, const int* in_sizes, int n_in,
                              void* d_out, int out_size, void* d_ws, size_t ws_size,
                              hipStream_t stream) {
  const float* q     = (const float*)d_in[0];
  const float* k     = (const float*)d_in[1];
  const float* v     = (const float*)d_in[2];
  const float* Wq    = (const float*)d_in[3];
  const float* bq    = (const float*)d_in[4];
  const float* Wk    = (const float*)d_in[5];
  const float* bk    = (const float*)d_in[6];
  const float* Wv_sh = (const float*)d_in[7];
  const float* Wv_sp = (const float*)d_in[8];
  const float* bv_sh = (const float*)d_in[9];
  const float* bv_sp = (const float*)d_in[10];
  const float* Wo_sh = (const float*)d_in[11];
  const float* Wo_sp = (const float*)d_in[12];
  const float* bo_sh = (const float*)d_in[13];
  const float* bo_sp = (const float*)d_in[14];
  const int*   mask  = (const int*)d_in[15];
  const int*   lang  = (const int*)d_in[16];

  char* ws = (char*)d_ws;
  size_t off = 0;
  auto alloc = [&](size_t bytes) -> char* {
    char* p = ws + off;
    off += (bytes + 255) & ~(size_t)255;
    return p;
  };
  u16* Qb   = (u16*)alloc((size_t)M_ * E_ * 2);
  u16* Kb   = (u16*)alloc((size_t)M_ * E_ * 2);
  u16* Vb   = (u16*)alloc((size_t)M_ * E_ * 2);
  u16* Vt   = (u16*)alloc((size_t)M_ * E_ * 2);
  u16* ctxb = (u16*)alloc((size_t)M_ * E_ * 2);
  u16* Wq_b = (u16*)alloc((size_t)E_ * E_ * 2);
  u16* Wk_b = (u16*)alloc((size_t)E_ * E_ * 2);
  u16* Wv_b = (u16*)alloc((size_t)E_ * E_ * 2);
  u16* Wo_b = (u16*)alloc((size_t)E_ * E_ * 2);
  float* bv_f = (float*)alloc(E_ * 4);
  float* bo_f = (float*)alloc(E_ * 4);

  prep_w<<<E_*E_/1024, 256, 0, stream>>>(Wq, Wk, Wv_sh, Wv_sp, Wo_sh, Wo_sp,
                                         bv_sh, bv_sp, bo_sh, bo_sp, lang,
                                         Wq_b, Wk_b, Wv_b, Wo_b, bv_f, bo_f);

  dim3 qkvgrid(512, 3);   // XCD-swizzled 1D work space x matrix select
  gemm_qkv<<<qkvgrid, 256, 0, stream>>>(q, k, v, Wq_b, Wk_b, Wv_b,
                                        bq, bk, bv_f, Qb, Kb, Vb);

  dim3 tgrid(S_/64, B_*H_);     // (16, 128)
  transpose_v<<<tgrid, 256, 0, stream>>>(Vb, Vt);

  attn_mfma<<<2048, 256, 0, stream>>>(Qb, Kb, Vt, mask, ctxb);

  gemm_lds<<<512, 256, 0, stream>>>(ctxb, Wo_b, bo_f, (float*)d_out);
}

// Round 3
// 309.888 us; speedup vs baseline: 1.0127x; 1.0007x over previous
//
#include <hip/hip_runtime.h>

#define B_ 16
#define S_ 1024
#define E_ 512
#define H_ 8
#define D_ 64
#define L_ 4
#define M_ (B_*S_)   // 16384 tokens

typedef unsigned short u16;
typedef __attribute__((ext_vector_type(8))) short bf16x8;  // 8 bf16 = 4 VGPRs
typedef __attribute__((ext_vector_type(4))) float f32x4;
typedef __attribute__((ext_vector_type(4))) unsigned uint4v;

__device__ __forceinline__ u16 f2bf(float x) {
  unsigned u = __float_as_uint(x);
  unsigned r = (u + 0x7fffu + ((u >> 16) & 1u)) >> 16;  // RNE
  return (u16)r;
}
__device__ __forceinline__ ushort4 f2bf4(float4 f) {
  ushort4 u;
  u.x = f2bf(f.x); u.y = f2bf(f.y); u.z = f2bf(f.z); u.w = f2bf(f.w);
  return u;
}
// single-instruction pack: two f32 -> packed bf16x2 (lo in low half)
__device__ __forceinline__ unsigned cvt_pk_bf16(float lo, float hi) {
  unsigned r;
  asm("v_cvt_pk_bf16_f32 %0, %1, %2" : "=v"(r) : "v"(lo), "v"(hi));
  return r;
}

typedef __attribute__((address_space(1))) const void gconst_void;
typedef __attribute__((address_space(3))) void lds_void;
__device__ __forceinline__ void gl_lds16(const void* g, void* l) {
  // async global->LDS, 16B per lane; LDS dest = wave-uniform base + lane*16
  __builtin_amdgcn_global_load_lds((gconst_void*)g, (lds_void*)l, 16, 0, 0);
}
__device__ __forceinline__ void fence_vm0_barrier() {
  // T4: drain only VMEM (global_load_lds), then raw barrier (no full syncthreads drain)
  asm volatile("s_waitcnt vmcnt(0)" ::: "memory");
  __builtin_amdgcn_s_barrier();
}

// ---------------- fused weight prep (all 4 weight matrices + biases) ----------------
__global__ __launch_bounds__(256) void prep_w(
    const float* __restrict__ Wq, const float* __restrict__ Wk,
    const float* __restrict__ Wv_sh, const float* __restrict__ Wv_sp,
    const float* __restrict__ Wo_sh, const float* __restrict__ Wo_sp,
    const float* __restrict__ bv_sh, const float* __restrict__ bv_sp,
    const float* __restrict__ bo_sh, const float* __restrict__ bo_sp,
    const int* __restrict__ langp,
    u16* __restrict__ Wq_b, u16* __restrict__ Wk_b,
    u16* __restrict__ Wv_b, u16* __restrict__ Wo_b,
    float* __restrict__ bv_f, float* __restrict__ bo_f) {
  int lang = langp[0];
  int i = blockIdx.x * 256 + threadIdx.x;           // over E_*E_/4
  size_t wofs = (size_t)lang * (E_*E_/4) + i;
  ((ushort4*)Wq_b)[i] = f2bf4(((const float4*)Wq)[i]);
  ((ushort4*)Wk_b)[i] = f2bf4(((const float4*)Wk)[i]);
  float4 vs = ((const float4*)Wv_sh)[i], vp = ((const float4*)Wv_sp)[wofs];
  float4 os = ((const float4*)Wo_sh)[i], op = ((const float4*)Wo_sp)[wofs];
  float4 vv = {vs.x*vp.x, vs.y*vp.y, vs.z*vp.z, vs.w*vp.w};
  float4 oo = {os.x*op.x, os.y*op.y, os.z*op.z, os.w*op.w};
  ((ushort4*)Wv_b)[i] = f2bf4(vv);
  ((ushort4*)Wo_b)[i] = f2bf4(oo);
  if (i < E_/4) {
    float4 b1 = ((const float4*)bv_sh)[i], b2 = ((const float4*)(bv_sp + (size_t)lang*E_))[i];
    float4 b3 = ((const float4*)bo_sh)[i], b4 = ((const float4*)(bo_sp + (size_t)lang*E_))[i];
    float4 r1 = {b1.x+b2.x, b1.y+b2.y, b1.z+b2.z, b1.w+b2.w};
    float4 r2 = {b3.x+b4.x, b3.y+b4.y, b3.z+b4.z, b3.w+b4.w};
    ((float4*)bv_f)[i] = r1;
    ((float4*)bo_f)[i] = r2;
  }
}

// ---------------- fused QKV projection GEMM: {Q,K,V}b = {q,k,v} @ W^T + b ----------------
// 2-phase double-buffered pipeline (T3 minimum): stage tile t+1 -> buf[(t+1)&1],
// compute tile t from buf[t&1], vmcnt(0)+raw barrier once per tile (never a full
// syncthreads drain). z==2 (V) writes the TRANSPOSED layout Vt[(b,h,d)][s] directly,
// eliminating the transpose_v kernel.
#define QBUF 4096   // 128*32 elements per buffer
__global__ __launch_bounds__(256) void gemm_qkv(
    const float* __restrict__ q, const float* __restrict__ k, const float* __restrict__ v,
    const u16* __restrict__ Wq_b, const u16* __restrict__ Wk_b, const u16* __restrict__ Wv_b,
    const float* __restrict__ bq, const float* __restrict__ bk, const float* __restrict__ bv,
    u16* __restrict__ Qb, u16* __restrict__ Kb, u16* __restrict__ Vt) {
  __shared__ __align__(16) float sAfD[2*QBUF];   // 32KB
  __shared__ __align__(16) u16   sBD[2*QBUF];    // 16KB
  const int z = blockIdx.y;
  const float* A    = (z == 0) ? q : (z == 1) ? k : v;
  const u16*   Bw   = (z == 0) ? Wq_b : (z == 1) ? Wk_b : Wv_b;
  const float* bias = (z == 0) ? bq : (z == 1) ? bk : bv;
  const int t = threadIdx.x;
  // XCD swizzle: 512 blocks, 8 XCDs, 64/chunk (512%8==0 -> bijective)
  const int hw = blockIdx.x;
  const int wk = (hw & 7) * 64 + (hw >> 3);
  const int m0 = (wk >> 2) * 128, n0 = (wk & 3) * 128;
  const int lane = t & 63, wid = t >> 6;
  const int m16 = lane & 15, qq = lane >> 4;
  const int wrow = (wid >> 1) * 64, wcol = (wid & 1) * 64;
  f32x4 acc[4][4] = {};
  // A staging: chunk ca = 1KB = 8 rows x 32 floats; lane l -> row ca*8+(l>>3), col (l&7)*4
  const int ca0 = wid*4;
  const float* ap[4];
#pragma unroll
  for (int i = 0; i < 4; ++i)
    ap[i] = A + (size_t)(m0 + (ca0+i)*8 + (lane >> 3)) * E_ + (lane & 7) * 4;
  // B staging: chunk cb = 512 u16 = 16 rows x 32; lane l -> row cb*16+(l>>2), col 8*(l&3)
  const int cb0 = wid*2, cb1 = wid*2 + 1;
  const u16* bp0 = Bw + (size_t)(n0 + cb0*16 + (lane >> 2)) * E_ + (lane & 3) * 8;
  const u16* bp1 = Bw + (size_t)(n0 + cb1*16 + (lane >> 2)) * E_ + (lane & 3) * 8;
  // prologue: stage tile 0 -> buf 0
  {
#pragma unroll
    for (int i = 0; i < 4; ++i) gl_lds16(ap[i], &sAfD[(ca0+i)*256]);
    gl_lds16(bp0, &sBD[cb0*512]);
    gl_lds16(bp1, &sBD[cb1*512]);
#pragma unroll
    for (int i = 0; i < 4; ++i) ap[i] += 32;
    bp0 += 32; bp1 += 32;
  }
  fence_vm0_barrier();
  for (int kt = 0; kt < 16; ++kt) {
    if (kt < 15) {      // issue next-tile loads BEFORE compute (latency hides under MFMA)
      float* sa = &sAfD[((kt+1)&1)*QBUF];
      u16*   sb = &sBD[((kt+1)&1)*QBUF];
#pragma unroll
      for (int i = 0; i < 4; ++i) gl_lds16(ap[i], sa + (ca0+i)*256);
      gl_lds16(bp0, sb + cb0*512);
      gl_lds16(bp1, sb + cb1*512);
#pragma unroll
      for (int i = 0; i < 4; ++i) ap[i] += 32;
      bp0 += 32; bp1 += 32;
    }
    const float* saf = &sAfD[(kt&1)*QBUF];
    const u16*   sbb = &sBD[(kt&1)*QBUF];
    bf16x8 af[4], bfm[4];
#pragma unroll
    for (int mt = 0; mt < 4; ++mt) {
      const float* ar = saf + (wrow + mt*16 + m16) * 32 + qq*8;
      f32x4 a0 = *(const f32x4*)ar;
      f32x4 a1 = *(const f32x4*)(ar + 4);
      union { uint4v u; bf16x8 h; } cv;
      cv.u = (uint4v){ cvt_pk_bf16(a0[0], a0[1]), cvt_pk_bf16(a0[2], a0[3]),
                       cvt_pk_bf16(a1[0], a1[1]), cvt_pk_bf16(a1[2], a1[3]) };
      af[mt] = cv.h;
    }
#pragma unroll
    for (int nt = 0; nt < 4; ++nt)
      bfm[nt] = *(const bf16x8*)(sbb + (wcol + nt*16 + m16) * 32 + qq*8);
#pragma unroll
    for (int mt = 0; mt < 4; ++mt)
#pragma unroll
      for (int nt = 0; nt < 4; ++nt)
        acc[mt][nt] = __builtin_amdgcn_mfma_f32_16x16x32_bf16(af[mt], bfm[nt], acc[mt][nt], 0, 0, 0);
    if (kt < 15) fence_vm0_barrier();
  }
  float bvv[4];
#pragma unroll
  for (int nt = 0; nt < 4; ++nt) bvv[nt] = bias[n0 + wcol + nt*16 + m16];
  if (z < 2) {
    u16* out = (z == 0) ? Qb : Kb;
#pragma unroll
    for (int mt = 0; mt < 4; ++mt) {
      int gm = m0 + wrow + mt*16 + qq*4;   // C/D: row = quad*4 + reg
#pragma unroll
      for (int nt = 0; nt < 4; ++nt) {
        int gn = n0 + wcol + nt*16 + m16;  // C/D: col = lane&15
#pragma unroll
        for (int r = 0; r < 4; ++r)
          out[(size_t)(gm + r) * E_ + gn] = f2bf(acc[mt][nt][r] + bvv[nt]);
      }
    }
  } else {
    // V: write transposed Vt[(b*E + dim)*S + s]; r=0..3 are consecutive tokens -> uint2 store
#pragma unroll
    for (int mt = 0; mt < 4; ++mt) {
      int tok0 = m0 + wrow + mt*16 + qq*4;
      int bb = tok0 >> 10, s0 = tok0 & 1023;
#pragma unroll
      for (int nt = 0; nt < 4; ++nt) {
        int dim = n0 + wcol + nt*16 + m16;
        uint2 wv = { cvt_pk_bf16(acc[mt][nt][0] + bvv[nt], acc[mt][nt][1] + bvv[nt]),
                     cvt_pk_bf16(acc[mt][nt][2] + bvv[nt], acc[mt][nt][3] + bvv[nt]) };
        *(uint2*)(Vt + ((size_t)(bb*E_ + dim))*S_ + s0) = wv;
      }
    }
  }
}

// ---------------- bf16 MFMA GEMM, 2-phase dbuf: Y = A @ Bw^T + bias, fp32 out ----------------
__global__ __launch_bounds__(256) void gemm_lds(
    const u16* __restrict__ A, const u16* __restrict__ Bw,
    const float* __restrict__ bias, float* __restrict__ out) {
  __shared__ __align__(16) u16 sAD[2*QBUF];   // 16KB
  __shared__ __align__(16) u16 sBD[2*QBUF];   // 16KB
  const int t = threadIdx.x;
  // XCD swizzle: 512 blocks, chunk=64/XCD
  const int hw = blockIdx.x;
  const int wk = (hw & 7) * 64 + (hw >> 3);
  const int m0 = (wk >> 2) * 128, n0 = (wk & 3) * 128;
  const int lane = t & 63, wid = t >> 6;
  const int m16 = lane & 15, qq = lane >> 4;
  const int wrow = (wid >> 1) * 64, wcol = (wid & 1) * 64;
  f32x4 acc[4][4] = {};
  const int c0 = 2*wid, c1 = 2*wid + 1;
  const int colk = (lane & 3) * 8;
  const int r0 = c0*16 + (lane >> 2), r1 = c1*16 + (lane >> 2);
  const u16* a0 = A  + (size_t)(m0 + r0) * E_ + colk;
  const u16* a1 = A  + (size_t)(m0 + r1) * E_ + colk;
  const u16* b0 = Bw + (size_t)(n0 + r0) * E_ + colk;
  const u16* b1 = Bw + (size_t)(n0 + r1) * E_ + colk;
  // prologue: tile 0 -> buf 0
  gl_lds16(a0, &sAD[c0*512]);
  gl_lds16(a1, &sAD[c1*512]);
  gl_lds16(b0, &sBD[c0*512]);
  gl_lds16(b1, &sBD[c1*512]);
  a0 += 32; a1 += 32; b0 += 32; b1 += 32;
  fence_vm0_barrier();
  for (int kt = 0; kt < 16; ++kt) {
    if (kt < 15) {
      u16* sa = &sAD[((kt+1)&1)*QBUF];
      u16* sb = &sBD[((kt+1)&1)*QBUF];
      gl_lds16(a0, sa + c0*512);
      gl_lds16(a1, sa + c1*512);
      gl_lds16(b0, sb + c0*512);
      gl_lds16(b1, sb + c1*512);
      a0 += 32; a1 += 32; b0 += 32; b1 += 32;
    }
    const u16* sa = &sAD[(kt&1)*QBUF];
    const u16* sb = &sBD[(kt&1)*QBUF];
    bf16x8 af[4], bfm[4];
#pragma unroll
    for (int mt = 0; mt < 4; ++mt)
      af[mt] = *(const bf16x8*)(sa + (wrow + mt*16 + m16) * 32 + qq*8);
#pragma unroll
    for (int nt = 0; nt < 4; ++nt)
      bfm[nt] = *(const bf16x8*)(sb + (wcol + nt*16 + m16) * 32 + qq*8);
#pragma unroll
    for (int mt = 0; mt < 4; ++mt)
#pragma unroll
      for (int nt = 0; nt < 4; ++nt)
        acc[mt][nt] = __builtin_amdgcn_mfma_f32_16x16x32_bf16(af[mt], bfm[nt], acc[mt][nt], 0, 0, 0);
    if (kt < 15) fence_vm0_barrier();
  }
  float bv[4];
#pragma unroll
  for (int nt = 0; nt < 4; ++nt) bv[nt] = bias[n0 + wcol + nt*16 + m16];
#pragma unroll
  for (int mt = 0; mt < 4; ++mt) {
    int gm = m0 + wrow + mt*16 + qq*4;
#pragma unroll
    for (int nt = 0; nt < 4; ++nt) {
      int gn = n0 + wcol + nt*16 + m16;
#pragma unroll
      for (int r = 0; r < 4; ++r)
        out[(size_t)(gm + r) * E_ + gn] = acc[mt][nt][r] + bv[nt];
    }
  }
}

// ---------------- MFMA flash attention (S^T operand order) ----------------
// Block = (b,h, 64 q-rows); 4 waves, wave w owns q-rows [w*16, w*16+16).
// QK^T computed as S^T = mfma(K, Q): C/D col=lane&15=qrow, row=quad*4+reg=key.
// -> each lane holds 4 CONSECUTIVE keys of one q-row: P written as packed b64.
// Fixed-shift softmax (scores bounded, masked -> exp2(-1e9)=0); l deferred.
// XCD-swizzled 1D grid (2048): all 16 q-blocks of a (b,h) + 16 consecutive bh
// (4MB of K/V = one L2) land on the same XCD.
#define KST 72   // padded LDS row stride (u16)
__global__ __launch_bounds__(256) void attn_mfma(
    const u16* __restrict__ Qb, const u16* __restrict__ Kb, const u16* __restrict__ Vt,
    const int* __restrict__ mask, u16* __restrict__ ctxb) {
  __shared__ __align__(16) u16 sK[64*KST];
  __shared__ __align__(16) u16 sV[64*KST];   // V^T tile: row=dim, col=key
  __shared__ __align__(16) u16 sP[64*KST];   // P tile (also final O staging)
  __shared__ __align__(16) float sMask[64];
  __shared__ __align__(16) float sL[64];
  const int t = threadIdx.x;
  const int lane = t & 63, w = t >> 6;
  const int m16 = lane & 15, quad = lane >> 4;
  // XCD swizzle: 2048 blocks, 8 XCDs, 256/chunk (bijective)
  const int hw = blockIdx.x;
  const int wk = (hw & 7) * 256 + (hw >> 3);
  const int bh = wk >> 4, b = bh >> 3, h = bh & 7;
  const int qblk = (wk & 15) * 64;
  const int q0 = qblk + w * 16;
  bf16x8 qf0, qf1;   // B-operand layout: n=lane&15=qrow, k=quad*8+j; two k-steps over D=64
  {
    const u16* qp = Qb + (size_t)(b*S_ + q0 + m16) * E_ + h*D_ + quad*8;
    qf0 = *(const bf16x8*)qp;
    qf1 = *(const bf16x8*)(qp + 32);
  }
  f32x4 oacc[4] = {};
  float lpart = 0.f;
  const int srow = t >> 2, sc0 = (t & 3) * 16;
  const u16* kp = Kb + (size_t)(b*S_ + srow) * E_ + h*D_ + sc0;
  const u16* vp = Vt + ((size_t)(b*H_ + h) * D_ + srow) * S_ + sc0;
  // preload tile 0 into registers
  uint4 rk0 = *(const uint4*)kp, rk1 = *(const uint4*)(kp + 8);
  uint4 rv0 = *(const uint4*)vp, rv1 = *(const uint4*)(vp + 8);
  float rmsk = 0.f;
  if (t < 64) rmsk = (mask[b*S_ + t] == 0) ? -1e9f : 0.f;
  const float CS = 0.015625f * 1.44269504f;   // (1/64)*log2(e)
  for (int kt = 0; kt < S_; kt += 64) {
    *(uint4*)&sK[srow*KST + sc0]     = rk0;
    *(uint4*)&sK[srow*KST + sc0 + 8] = rk1;
    *(uint4*)&sV[srow*KST + sc0]     = rv0;
    *(uint4*)&sV[srow*KST + sc0 + 8] = rv1;
    if (t < 64) sMask[t] = rmsk;
    __syncthreads();
    // prefetch next tile (latency hidden behind this tile's compute)
    if (kt + 64 < S_) {
      kp += (size_t)64 * E_; vp += 64;
      rk0 = *(const uint4*)kp; rk1 = *(const uint4*)(kp + 8);
      rv0 = *(const uint4*)vp; rv1 = *(const uint4*)(vp + 8);
      if (t < 64) rmsk = (mask[b*S_ + kt + 64 + t] == 0) ? -1e9f : 0.f;
    }
    // ---- S^T = K Q^T : A=K (m=key), B=Q (n=qrow); 4 key-tiles x 2 k-steps ----
    f32x4 sacc[4] = {};
#pragma unroll
    for (int ct = 0; ct < 4; ++ct) {
      bf16x8 kf0 = *(const bf16x8*)&sK[(ct*16 + m16)*KST + quad*8];
      bf16x8 kf1 = *(const bf16x8*)&sK[(ct*16 + m16)*KST + 32 + quad*8];
      sacc[ct] = __builtin_amdgcn_mfma_f32_16x16x32_bf16(kf0, qf0, sacc[ct], 0, 0, 0);
      sacc[ct] = __builtin_amdgcn_mfma_f32_16x16x32_bf16(kf1, qf1, sacc[ct], 0, 0, 0);
    }
    // ---- softmax: lane has keys ct*16+quad*4+r for q-row m16 ----
#pragma unroll
    for (int ct = 0; ct < 4; ++ct) {
      f32x4 msk = *(const f32x4*)&sMask[ct*16 + quad*4];
      float p0 = exp2f(fmaf(sacc[ct][0], CS, msk[0]));
      float p1 = exp2f(fmaf(sacc[ct][1], CS, msk[1]));
      float p2 = exp2f(fmaf(sacc[ct][2], CS, msk[2]));
      float p3 = exp2f(fmaf(sacc[ct][3], CS, msk[3]));
      lpart += (p0 + p1) + (p2 + p3);
      uint2 pq = { cvt_pk_bf16(p0, p1), cvt_pk_bf16(p2, p3) };
      *(uint2*)&sP[(w*16 + m16)*KST + ct*16 + quad*4] = pq;  // A-layout, b64, wave-private
    }
    bf16x8 pf0 = *(const bf16x8*)&sP[(w*16 + m16)*KST + quad*8];
    bf16x8 pf1 = *(const bf16x8*)&sP[(w*16 + m16)*KST + 32 + quad*8];
    // ---- O += P V : A=P (m=qrow), B=V^T (n=dim); 4 dim-tiles x 2 k-steps ----
#pragma unroll
    for (int dt = 0; dt < 4; ++dt) {
      bf16x8 vf0 = *(const bf16x8*)&sV[(dt*16 + m16)*KST + quad*8];
      bf16x8 vf1 = *(const bf16x8*)&sV[(dt*16 + m16)*KST + 32 + quad*8];
      oacc[dt] = __builtin_amdgcn_mfma_f32_16x16x32_bf16(pf0, vf0, oacc[dt], 0, 0, 0);
      oacc[dt] = __builtin_amdgcn_mfma_f32_16x16x32_bf16(pf1, vf1, oacc[dt], 0, 0, 0);
    }
    __syncthreads();   // all waves done reading sK/sV before next staging
  }
  // ---- deferred l reduction: sum quad groups (lane's lpart is for qrow=m16) ----
  lpart += __shfl_xor(lpart, 16);
  lpart += __shfl_xor(lpart, 32);
  if (quad == 0) sL[w*16 + m16] = lpart;     // wave-private broadcast buffer
  // oacc C-layout: row(qrow)=quad*4+r, col(dim)=dt*16+m16 -> need l for quad*4+r
  float inv[4];
#pragma unroll
  for (int r = 0; r < 4; ++r) inv[r] = 1.0f / sL[w*16 + quad*4 + r];
  // ---- epilogue: normalize, stage in sP (wave-private rows), coalesced store ----
#pragma unroll
  for (int dt = 0; dt < 4; ++dt)
#pragma unroll
    for (int r = 0; r < 4; ++r)
      sP[(w*16 + quad*4 + r)*KST + dt*16 + m16] = f2bf(oacc[dt][r] * inv[r]);
  __syncthreads();
  const int orow = t >> 2, oc0 = (t & 3) * 16;
  uint4 o0 = *(uint4*)&sP[orow*KST + oc0];
  uint4 o1 = *(uint4*)&sP[orow*KST + oc0 + 8];
  u16* dst = ctxb + (size_t)(b*S_ + qblk + orow) * E_ + h*D_ + oc0;
  *(uint4*)dst = o0;
  *(uint4*)(dst + 8) = o1;
}

// ---------------- launch ----------------
extern "C" void kernel_launch(void* const* d_in, const int* in_sizes, int n_in,
                              void* d_out, int out_size, void* d_ws, size_t ws_size,
                              hipStream_t stream) {
  const float* q     = (const float*)d_in[0];
  const float* k     = (const float*)d_in[1];
  const float* v     = (const float*)d_in[2];
  const float* Wq    = (const float*)d_in[3];
  const float* bq    = (const float*)d_in[4];
  const float* Wk    = (const float*)d_in[5];
  const float* bk    = (const float*)d_in[6];
  const float* Wv_sh = (const float*)d_in[7];
  const float* Wv_sp = (const float*)d_in[8];
  const float* bv_sh = (const float*)d_in[9];
  const float* bv_sp = (const float*)d_in[10];
  const float* Wo_sh = (const float*)d_in[11];
  const float* Wo_sp = (const float*)d_in[12];
  const float* bo_sh = (const float*)d_in[13];
  const float* bo_sp = (const float*)d_in[14];
  const int*   mask  = (const int*)d_in[15];
  const int*   lang  = (const int*)d_in[16];

  char* ws = (char*)d_ws;
  size_t off = 0;
  auto alloc = [&](size_t bytes) -> char* {
    char* p = ws + off;
    off += (bytes + 255) & ~(size_t)255;
    return p;
  };
  u16* Qb   = (u16*)alloc((size_t)M_ * E_ * 2);
  u16* Kb   = (u16*)alloc((size_t)M_ * E_ * 2);
  u16* Vt   = (u16*)alloc((size_t)M_ * E_ * 2);
  u16* ctxb = (u16*)alloc((size_t)M_ * E_ * 2);
  u16* Wq_b = (u16*)alloc((size_t)E_ * E_ * 2);
  u16* Wk_b = (u16*)alloc((size_t)E_ * E_ * 2);
  u16* Wv_b = (u16*)alloc((size_t)E_ * E_ * 2);
  u16* Wo_b = (u16*)alloc((size_t)E_ * E_ * 2);
  float* bv_f = (float*)alloc(E_ * 4);
  float* bo_f = (float*)alloc(E_ * 4);

  prep_w<<<E_*E_/1024, 256, 0, stream>>>(Wq, Wk, Wv_sh, Wv_sp, Wo_sh, Wo_sp,
                                         bv_sh, bv_sp, bo_sh, bo_sp, lang,
                                         Wq_b, Wk_b, Wv_b, Wo_b, bv_f, bo_f);

  dim3 qkvgrid(512, 3);   // XCD-swizzled 1D work space x matrix select
  gemm_qkv<<<qkvgrid, 256, 0, stream>>>(q, k, v, Wq_b, Wk_b, Wv_b,
                                        bq, bk, bv_f, Qb, Kb, Vt);

  attn_mfma<<<2048, 256, 0, stream>>>(Qb, Kb, Vt, mask, ctxb);

  gemm_lds<<<512, 256, 0, stream>>>(ctxb, Wo_b, bo_f, (float*)d_out);
}

// Round 4
// 301.954 us; speedup vs baseline: 1.0393x; 1.0263x over previous
//
#include <hip/hip_runtime.h>

#define B_ 16
#define S_ 1024
#define E_ 512
#define H_ 8
#define D_ 64
#define L_ 4
#define M_ (B_*S_)   // 16384 tokens

typedef unsigned short u16;
typedef __attribute__((ext_vector_type(8))) short bf16x8;  // 8 bf16 = 4 VGPRs
typedef __attribute__((ext_vector_type(4))) float f32x4;
typedef __attribute__((ext_vector_type(4))) unsigned uint4v;

__device__ __forceinline__ u16 f2bf(float x) {
  unsigned u = __float_as_uint(x);
  unsigned r = (u + 0x7fffu + ((u >> 16) & 1u)) >> 16;  // RNE
  return (u16)r;
}
__device__ __forceinline__ ushort4 f2bf4(float4 f) {
  ushort4 u;
  u.x = f2bf(f.x); u.y = f2bf(f.y); u.z = f2bf(f.z); u.w = f2bf(f.w);
  return u;
}
// single-instruction pack: two f32 -> packed bf16x2 (lo in low half)
__device__ __forceinline__ unsigned cvt_pk_bf16(float lo, float hi) {
  unsigned r;
  asm("v_cvt_pk_bf16_f32 %0, %1, %2" : "=v"(r) : "v"(lo), "v"(hi));
  return r;
}

typedef __attribute__((address_space(1))) const void gconst_void;
typedef __attribute__((address_space(3))) void lds_void;
__device__ __forceinline__ void gl_lds16(const void* g, void* l) {
  // async global->LDS, 16B per lane; LDS dest = wave-uniform base + lane*16
  __builtin_amdgcn_global_load_lds((gconst_void*)g, (lds_void*)l, 16, 0, 0);
}
__device__ __forceinline__ void fence_vm0_barrier() {
  asm volatile("s_waitcnt vmcnt(0)" ::: "memory");
  __builtin_amdgcn_s_barrier();
}

// LDS XOR swizzle for 64B-row bf16 tiles: g(row,col)=(row*64+col)^((row&7)<<4).
// Read of b128 at (row, qq*16B): fixed quad sees 8 distinct bank-groups -> 2-way (free).
// Inverse mapping for global_load_lds staging (lane l writes LDS byte chunk+16*l):
//   row0 = ((l>>2)&1) ^ ((l>>4)&1); row_in_chunk = 2*(l>>3)+row0;
//   col_u16 = ((l&1)^row0)*8 + (((l>>1)&1)^((l>>3)&1))*16;
// (hand-verified: lanes 0,1,4,8,12,16 all satisfy g(row,col)=chunk+16*l)

// ---------------- fused weight prep (all 4 weight matrices + biases) ----------------
__global__ __launch_bounds__(256) void prep_w(
    const float* __restrict__ Wq, const float* __restrict__ Wk,
    const float* __restrict__ Wv_sh, const float* __restrict__ Wv_sp,
    const float* __restrict__ Wo_sh, const float* __restrict__ Wo_sp,
    const float* __restrict__ bv_sh, const float* __restrict__ bv_sp,
    const float* __restrict__ bo_sh, const float* __restrict__ bo_sp,
    const int* __restrict__ langp,
    u16* __restrict__ Wq_b, u16* __restrict__ Wk_b,
    u16* __restrict__ Wv_b, u16* __restrict__ Wo_b,
    float* __restrict__ bv_f, float* __restrict__ bo_f) {
  int lang = langp[0];
  int i = blockIdx.x * 256 + threadIdx.x;           // over E_*E_/4
  size_t wofs = (size_t)lang * (E_*E_/4) + i;
  ((ushort4*)Wq_b)[i] = f2bf4(((const float4*)Wq)[i]);
  ((ushort4*)Wk_b)[i] = f2bf4(((const float4*)Wk)[i]);
  float4 vs = ((const float4*)Wv_sh)[i], vp = ((const float4*)Wv_sp)[wofs];
  float4 os = ((const float4*)Wo_sh)[i], op = ((const float4*)Wo_sp)[wofs];
  float4 vv = {vs.x*vp.x, vs.y*vp.y, vs.z*vp.z, vs.w*vp.w};
  float4 oo = {os.x*op.x, os.y*op.y, os.z*op.z, os.w*op.w};
  ((ushort4*)Wv_b)[i] = f2bf4(vv);
  ((ushort4*)Wo_b)[i] = f2bf4(oo);
  if (i < E_/4) {
    float4 b1 = ((const float4*)bv_sh)[i], b2 = ((const float4*)(bv_sp + (size_t)lang*E_))[i];
    float4 b3 = ((const float4*)bo_sh)[i], b4 = ((const float4*)(bo_sp + (size_t)lang*E_))[i];
    float4 r1 = {b1.x+b2.x, b1.y+b2.y, b1.z+b2.z, b1.w+b2.w};
    float4 r2 = {b3.x+b4.x, b3.y+b4.y, b3.z+b4.z, b3.w+b4.w};
    ((float4*)bv_f)[i] = r1;
    ((float4*)bo_f)[i] = r2;
  }
}

// ---------------- fused QKV projection GEMM: {Q,K,V}b = {q,k,v} @ W^T + b ----------------
// 128x128 tile, BK=32, 4 waves 2x2, dbuf. A (fp32) is reg-staged: global->reg,
// cvt to bf16 at STAGE time, swizzled ds_write (T14 split: loads issued before
// compute, writes after). B staged via global_load_lds with inverse-swizzled
// source. All LDS reads conflict-free via XOR swizzle. z==2 (V) writes the
// transposed layout Vt[(b,h,d)][s] directly.
#define ABBUF 8192   // bytes per LDS buffer (128 rows x 64B)
__global__ __launch_bounds__(256, 4) void gemm_qkv(
    const float* __restrict__ q, const float* __restrict__ k, const float* __restrict__ v,
    const u16* __restrict__ Wq_b, const u16* __restrict__ Wk_b, const u16* __restrict__ Wv_b,
    const float* __restrict__ bq, const float* __restrict__ bk, const float* __restrict__ bv,
    u16* __restrict__ Qb, u16* __restrict__ Kb, u16* __restrict__ Vt) {
  __shared__ __align__(16) u16 sA[2*4096];   // 16KB (bf16 A, dbuf)
  __shared__ __align__(16) u16 sB[2*4096];   // 16KB
  const int z = blockIdx.y;
  const float* A    = (z == 0) ? q : (z == 1) ? k : v;
  const u16*   Bw   = (z == 0) ? Wq_b : (z == 1) ? Wk_b : Wv_b;
  const float* bias = (z == 0) ? bq : (z == 1) ? bk : bv;
  const int t = threadIdx.x;
  // XCD swizzle: 512 blocks, 8 XCDs, 64/chunk (bijective)
  const int hw = blockIdx.x;
  const int wk = (hw & 7) * 64 + (hw >> 3);
  const int m0 = (wk >> 2) * 128, n0 = (wk & 3) * 128;
  const int lane = t & 63, wid = t >> 6;
  const int m16 = lane & 15, qq = lane >> 4;
  const int wrow = (wid >> 1) * 64, wcol = (wid & 1) * 64;
  const int key = (lane & 7) << 4;    // read-side swizzle (row&7 == lane&7 for all frags)
  f32x4 acc[4][4] = {};
  // ---- A reg-staging: thread t owns row t>>1, 16 floats at col (t&1)*16 ----
  const int arow = t >> 1;
  const float* aR = A + (size_t)(m0 + arow) * E_ + (t & 1) * 16;
  const int awr0 = (arow*64 + (t&1)*32)      ^ ((arow & 7) << 4);
  const int awr1 = (arow*64 + (t&1)*32 + 16) ^ ((arow & 7) << 4);
  // ---- B staging: gload_lds, inverse-swizzled source ----
  const int cb0 = wid*2, cb1 = wid*2 + 1;
  const int rl0 = ((lane>>2)&1) ^ ((lane>>4)&1);
  const int brow = 2*(lane>>3) + rl0;
  const int bcol = (((lane&1)^rl0)<<3) + ((((lane>>1)&1) ^ ((lane>>3)&1))<<4);
  const u16* bp0 = Bw + (size_t)(n0 + cb0*16 + brow) * E_ + bcol;
  const u16* bp1 = Bw + (size_t)(n0 + cb1*16 + brow) * E_ + bcol;
  char* sAb = (char*)sA;
  char* sBb = (char*)sB;
  // ---- prologue: tile 0 -> buf 0 ----
  gl_lds16(bp0, sBb + cb0*1024);
  gl_lds16(bp1, sBb + cb1*1024);
  f32x4 ar0 = *(const f32x4*)aR;
  f32x4 ar1 = *(const f32x4*)(aR + 4);
  f32x4 ar2 = *(const f32x4*)(aR + 8);
  f32x4 ar3 = *(const f32x4*)(aR + 12);
  aR += 32; bp0 += 32; bp1 += 32;
  asm volatile("s_waitcnt vmcnt(0)" ::: "memory");
  {
    uint4v w0 = { cvt_pk_bf16(ar0[0],ar0[1]), cvt_pk_bf16(ar0[2],ar0[3]),
                  cvt_pk_bf16(ar1[0],ar1[1]), cvt_pk_bf16(ar1[2],ar1[3]) };
    uint4v w1 = { cvt_pk_bf16(ar2[0],ar2[1]), cvt_pk_bf16(ar2[2],ar2[3]),
                  cvt_pk_bf16(ar3[0],ar3[1]), cvt_pk_bf16(ar3[2],ar3[3]) };
    *(uint4v*)(sAb + awr0) = w0;
    *(uint4v*)(sAb + awr1) = w1;
  }
  asm volatile("s_waitcnt lgkmcnt(0)" ::: "memory");
  __builtin_amdgcn_s_barrier();
  for (int kt = 0; kt < 16; ++kt) {
    const int cur = (kt & 1) * ABBUF;
    const int nxt = ABBUF - cur;
    if (kt < 15) {   // issue next-tile loads BEFORE compute
      gl_lds16(bp0, sBb + nxt + cb0*1024);
      gl_lds16(bp1, sBb + nxt + cb1*1024);
      ar0 = *(const f32x4*)aR;
      ar1 = *(const f32x4*)(aR + 4);
      ar2 = *(const f32x4*)(aR + 8);
      ar3 = *(const f32x4*)(aR + 12);
      aR += 32; bp0 += 32; bp1 += 32;
    }
    bf16x8 af[4], bfm[4];
#pragma unroll
    for (int mt = 0; mt < 4; ++mt) {
      int row = wrow + mt*16 + m16;
      af[mt] = *(const bf16x8*)(sAb + cur + ((row*64 + qq*16) ^ key));
    }
#pragma unroll
    for (int nt = 0; nt < 4; ++nt) {
      int row = wcol + nt*16 + m16;
      bfm[nt] = *(const bf16x8*)(sBb + cur + ((row*64 + qq*16) ^ key));
    }
#pragma unroll
    for (int mt = 0; mt < 4; ++mt)
#pragma unroll
      for (int nt = 0; nt < 4; ++nt)
        acc[mt][nt] = __builtin_amdgcn_mfma_f32_16x16x32_bf16(af[mt], bfm[nt], acc[mt][nt], 0, 0, 0);
    if (kt < 15) {   // write A tile kt+1 into nxt, then publish
      asm volatile("s_waitcnt vmcnt(0)" ::: "memory");
      uint4v w0 = { cvt_pk_bf16(ar0[0],ar0[1]), cvt_pk_bf16(ar0[2],ar0[3]),
                    cvt_pk_bf16(ar1[0],ar1[1]), cvt_pk_bf16(ar1[2],ar1[3]) };
      uint4v w1 = { cvt_pk_bf16(ar2[0],ar2[1]), cvt_pk_bf16(ar2[2],ar2[3]),
                    cvt_pk_bf16(ar3[0],ar3[1]), cvt_pk_bf16(ar3[2],ar3[3]) };
      *(uint4v*)(sAb + nxt + awr0) = w0;
      *(uint4v*)(sAb + nxt + awr1) = w1;
      asm volatile("s_waitcnt lgkmcnt(0)" ::: "memory");
      __builtin_amdgcn_s_barrier();
    }
  }
  float bvv[4];
#pragma unroll
  for (int nt = 0; nt < 4; ++nt) bvv[nt] = bias[n0 + wcol + nt*16 + m16];
  if (z < 2) {
    u16* out = (z == 0) ? Qb : Kb;
#pragma unroll
    for (int mt = 0; mt < 4; ++mt) {
      int gm = m0 + wrow + mt*16 + qq*4;   // C/D: row = quad*4 + reg
#pragma unroll
      for (int nt = 0; nt < 4; ++nt) {
        int gn = n0 + wcol + nt*16 + m16;  // C/D: col = lane&15
#pragma unroll
        for (int r = 0; r < 4; ++r)
          out[(size_t)(gm + r) * E_ + gn] = f2bf(acc[mt][nt][r] + bvv[nt]);
      }
    }
  } else {
    // V: write transposed Vt[(b*E + dim)*S + s]; r=0..3 consecutive tokens -> uint2 store
#pragma unroll
    for (int mt = 0; mt < 4; ++mt) {
      int tok0 = m0 + wrow + mt*16 + qq*4;
      int bb = tok0 >> 10, s0 = tok0 & 1023;
#pragma unroll
      for (int nt = 0; nt < 4; ++nt) {
        int dim = n0 + wcol + nt*16 + m16;
        uint2 wv = { cvt_pk_bf16(acc[mt][nt][0] + bvv[nt], acc[mt][nt][1] + bvv[nt]),
                     cvt_pk_bf16(acc[mt][nt][2] + bvv[nt], acc[mt][nt][3] + bvv[nt]) };
        *(uint2*)(Vt + ((size_t)(bb*E_ + dim))*S_ + s0) = wv;
      }
    }
  }
}

// ---------------- bf16 MFMA GEMM, 128x64 tile (4/CU), swizzled, dbuf ----------------
// Y = A @ Bw^T + bias, fp32 out. Grid 1024 = 128 m-tiles x 8 n-tiles.
__global__ __launch_bounds__(256, 4) void gemm_lds(
    const u16* __restrict__ A, const u16* __restrict__ Bw,
    const float* __restrict__ bias, float* __restrict__ out) {
  __shared__ __align__(16) u16 sAD[2*4096];   // 16KB (128 rows x 64B, dbuf)
  __shared__ __align__(16) u16 sBD[2*2048];   // 8KB  (64 rows x 64B, dbuf)
  const int t = threadIdx.x;
  // XCD swizzle: 1024 blocks, 8 XCDs, 128/chunk (bijective)
  const int hw = blockIdx.x;
  const int wk = (hw & 7) * 128 + (hw >> 3);
  const int m0 = (wk >> 3) * 128, n0 = (wk & 7) * 64;
  const int lane = t & 63, wid = t >> 6;
  const int m16 = lane & 15, qq = lane >> 4;
  const int wrow = (wid >> 1) * 64, wcol = (wid & 1) * 32;
  const int key = (lane & 7) << 4;
  f32x4 acc[4][2] = {};
  // staging: A chunks 2*wid, 2*wid+1 (8 x 1KB); B chunk wid (4 x 1KB)
  const int rl0 = ((lane>>2)&1) ^ ((lane>>4)&1);
  const int brow = 2*(lane>>3) + rl0;
  const int bcol = (((lane&1)^rl0)<<3) + ((((lane>>1)&1) ^ ((lane>>3)&1))<<4);
  const int c0 = 2*wid, c1 = 2*wid + 1;
  const u16* a0 = A  + (size_t)(m0 + c0*16 + brow) * E_ + bcol;
  const u16* a1 = A  + (size_t)(m0 + c1*16 + brow) * E_ + bcol;
  const u16* b0 = Bw + (size_t)(n0 + wid*16 + brow) * E_ + bcol;
  char* sAb = (char*)sAD;
  char* sBb = (char*)sBD;
  // prologue: tile 0 -> buf 0
  gl_lds16(a0, sAb + c0*1024);
  gl_lds16(a1, sAb + c1*1024);
  gl_lds16(b0, sBb + wid*1024);
  a0 += 32; a1 += 32; b0 += 32;
  fence_vm0_barrier();
  for (int kt = 0; kt < 16; ++kt) {
    const int curA = (kt & 1) * 8192, nxtA = 8192 - curA;
    const int curB = (kt & 1) * 4096, nxtB = 4096 - curB;
    if (kt < 15) {
      gl_lds16(a0, sAb + nxtA + c0*1024);
      gl_lds16(a1, sAb + nxtA + c1*1024);
      gl_lds16(b0, sBb + nxtB + wid*1024);
      a0 += 32; a1 += 32; b0 += 32;
    }
    bf16x8 af[4], bfm[2];
#pragma unroll
    for (int mt = 0; mt < 4; ++mt) {
      int row = wrow + mt*16 + m16;
      af[mt] = *(const bf16x8*)(sAb + curA + ((row*64 + qq*16) ^ key));
    }
#pragma unroll
    for (int nt = 0; nt < 2; ++nt) {
      int row = wcol + nt*16 + m16;
      bfm[nt] = *(const bf16x8*)(sBb + curB + ((row*64 + qq*16) ^ key));
    }
#pragma unroll
    for (int mt = 0; mt < 4; ++mt)
#pragma unroll
      for (int nt = 0; nt < 2; ++nt)
        acc[mt][nt] = __builtin_amdgcn_mfma_f32_16x16x32_bf16(af[mt], bfm[nt], acc[mt][nt], 0, 0, 0);
    if (kt < 15) fence_vm0_barrier();
  }
  float bv[2];
#pragma unroll
  for (int nt = 0; nt < 2; ++nt) bv[nt] = bias[n0 + wcol + nt*16 + m16];
#pragma unroll
  for (int mt = 0; mt < 4; ++mt) {
    int gm = m0 + wrow + mt*16 + qq*4;
#pragma unroll
    for (int nt = 0; nt < 2; ++nt) {
      int gn = n0 + wcol + nt*16 + m16;
#pragma unroll
      for (int r = 0; r < 4; ++r)
        out[(size_t)(gm + r) * E_ + gn] = acc[mt][nt][r] + bv[nt];
    }
  }
}

// ---------------- MFMA flash attention (S^T operand order) ----------------
// Block = (b,h, 64 q-rows); 4 waves, wave w owns q-rows [w*16, w*16+16).
// QK^T computed as S^T = mfma(K, Q): C/D col=lane&15=qrow, row=quad*4+reg=key.
// Fixed-shift softmax (scores bounded, masked -> exp2(-1e9)=0); l deferred.
// XCD-swizzled 1D grid (2048).
#define KST 72   // padded LDS row stride (u16)
__global__ __launch_bounds__(256) void attn_mfma(
    const u16* __restrict__ Qb, const u16* __restrict__ Kb, const u16* __restrict__ Vt,
    const int* __restrict__ mask, u16* __restrict__ ctxb) {
  __shared__ __align__(16) u16 sK[64*KST];
  __shared__ __align__(16) u16 sV[64*KST];   // V^T tile: row=dim, col=key
  __shared__ __align__(16) u16 sP[64*KST];   // P tile (also final O staging)
  __shared__ __align__(16) float sMask[64];
  __shared__ __align__(16) float sL[64];
  const int t = threadIdx.x;
  const int lane = t & 63, w = t >> 6;
  const int m16 = lane & 15, quad = lane >> 4;
  const int hw = blockIdx.x;
  const int wk = (hw & 7) * 256 + (hw >> 3);
  const int bh = wk >> 4, b = bh >> 3, h = bh & 7;
  const int qblk = (wk & 15) * 64;
  const int q0 = qblk + w * 16;
  bf16x8 qf0, qf1;   // B-operand layout: n=lane&15=qrow, k=quad*8+j
  {
    const u16* qp = Qb + (size_t)(b*S_ + q0 + m16) * E_ + h*D_ + quad*8;
    qf0 = *(const bf16x8*)qp;
    qf1 = *(const bf16x8*)(qp + 32);
  }
  f32x4 oacc[4] = {};
  float lpart = 0.f;
  const int srow = t >> 2, sc0 = (t & 3) * 16;
  const u16* kp = Kb + (size_t)(b*S_ + srow) * E_ + h*D_ + sc0;
  const u16* vp = Vt + ((size_t)(b*H_ + h) * D_ + srow) * S_ + sc0;
  uint4 rk0 = *(const uint4*)kp, rk1 = *(const uint4*)(kp + 8);
  uint4 rv0 = *(const uint4*)vp, rv1 = *(const uint4*)(vp + 8);
  float rmsk = 0.f;
  if (t < 64) rmsk = (mask[b*S_ + t] == 0) ? -1e9f : 0.f;
  const float CS = 0.015625f * 1.44269504f;   // (1/64)*log2(e)
  for (int kt = 0; kt < S_; kt += 64) {
    *(uint4*)&sK[srow*KST + sc0]     = rk0;
    *(uint4*)&sK[srow*KST + sc0 + 8] = rk1;
    *(uint4*)&sV[srow*KST + sc0]     = rv0;
    *(uint4*)&sV[srow*KST + sc0 + 8] = rv1;
    if (t < 64) sMask[t] = rmsk;
    __syncthreads();
    if (kt + 64 < S_) {
      kp += (size_t)64 * E_; vp += 64;
      rk0 = *(const uint4*)kp; rk1 = *(const uint4*)(kp + 8);
      rv0 = *(const uint4*)vp; rv1 = *(const uint4*)(vp + 8);
      if (t < 64) rmsk = (mask[b*S_ + kt + 64 + t] == 0) ? -1e9f : 0.f;
    }
    f32x4 sacc[4] = {};
#pragma unroll
    for (int ct = 0; ct < 4; ++ct) {
      bf16x8 kf0 = *(const bf16x8*)&sK[(ct*16 + m16)*KST + quad*8];
      bf16x8 kf1 = *(const bf16x8*)&sK[(ct*16 + m16)*KST + 32 + quad*8];
      sacc[ct] = __builtin_amdgcn_mfma_f32_16x16x32_bf16(kf0, qf0, sacc[ct], 0, 0, 0);
      sacc[ct] = __builtin_amdgcn_mfma_f32_16x16x32_bf16(kf1, qf1, sacc[ct], 0, 0, 0);
    }
#pragma unroll
    for (int ct = 0; ct < 4; ++ct) {
      f32x4 msk = *(const f32x4*)&sMask[ct*16 + quad*4];
      float p0 = exp2f(fmaf(sacc[ct][0], CS, msk[0]));
      float p1 = exp2f(fmaf(sacc[ct][1], CS, msk[1]));
      float p2 = exp2f(fmaf(sacc[ct][2], CS, msk[2]));
      float p3 = exp2f(fmaf(sacc[ct][3], CS, msk[3]));
      lpart += (p0 + p1) + (p2 + p3);
      uint2 pq = { cvt_pk_bf16(p0, p1), cvt_pk_bf16(p2, p3) };
      *(uint2*)&sP[(w*16 + m16)*KST + ct*16 + quad*4] = pq;
    }
    bf16x8 pf0 = *(const bf16x8*)&sP[(w*16 + m16)*KST + quad*8];
    bf16x8 pf1 = *(const bf16x8*)&sP[(w*16 + m16)*KST + 32 + quad*8];
#pragma unroll
    for (int dt = 0; dt < 4; ++dt) {
      bf16x8 vf0 = *(const bf16x8*)&sV[(dt*16 + m16)*KST + quad*8];
      bf16x8 vf1 = *(const bf16x8*)&sV[(dt*16 + m16)*KST + 32 + quad*8];
      oacc[dt] = __builtin_amdgcn_mfma_f32_16x16x32_bf16(pf0, vf0, oacc[dt], 0, 0, 0);
      oacc[dt] = __builtin_amdgcn_mfma_f32_16x16x32_bf16(pf1, vf1, oacc[dt], 0, 0, 0);
    }
    __syncthreads();
  }
  lpart += __shfl_xor(lpart, 16);
  lpart += __shfl_xor(lpart, 32);
  if (quad == 0) sL[w*16 + m16] = lpart;
  float inv[4];
#pragma unroll
  for (int r = 0; r < 4; ++r) inv[r] = 1.0f / sL[w*16 + quad*4 + r];
#pragma unroll
  for (int dt = 0; dt < 4; ++dt)
#pragma unroll
    for (int r = 0; r < 4; ++r)
      sP[(w*16 + quad*4 + r)*KST + dt*16 + m16] = f2bf(oacc[dt][r] * inv[r]);
  __syncthreads();
  const int orow = t >> 2, oc0 = (t & 3) * 16;
  uint4 o0 = *(uint4*)&sP[orow*KST + oc0];
  uint4 o1 = *(uint4*)&sP[orow*KST + oc0 + 8];
  u16* dst = ctxb + (size_t)(b*S_ + qblk + orow) * E_ + h*D_ + oc0;
  *(uint4*)dst = o0;
  *(uint4*)(dst + 8) = o1;
}

// ---------------- launch ----------------
extern "C" void kernel_launch(void* const* d_in, const int* in_sizes, int n_in,
                              void* d_out, int out_size, void* d_ws, size_t ws_size,
                              hipStream_t stream) {
  const float* q     = (const float*)d_in[0];
  const float* k     = (const float*)d_in[1];
  const float* v     = (const float*)d_in[2];
  const float* Wq    = (const float*)d_in[3];
  const float* bq    = (const float*)d_in[4];
  const float* Wk    = (const float*)d_in[5];
  const float* bk    = (const float*)d_in[6];
  const float* Wv_sh = (const float*)d_in[7];
  const float* Wv_sp = (const float*)d_in[8];
  const float* bv_sh = (const float*)d_in[9];
  const float* bv_sp = (const float*)d_in[10];
  const float* Wo_sh = (const float*)d_in[11];
  const float* Wo_sp = (const float*)d_in[12];
  const float* bo_sh = (const float*)d_in[13];
  const float* bo_sp = (const float*)d_in[14];
  const int*   mask  = (const int*)d_in[15];
  const int*   lang  = (const int*)d_in[16];

  char* ws = (char*)d_ws;
  size_t off = 0;
  auto alloc = [&](size_t bytes) -> char* {
    char* p = ws + off;
    off += (bytes + 255) & ~(size_t)255;
    return p;
  };
  u16* Qb   = (u16*)alloc((size_t)M_ * E_ * 2);
  u16* Kb   = (u16*)alloc((size_t)M_ * E_ * 2);
  u16* Vt   = (u16*)alloc((size_t)M_ * E_ * 2);
  u16* ctxb = (u16*)alloc((size_t)M_ * E_ * 2);
  u16* Wq_b = (u16*)alloc((size_t)E_ * E_ * 2);
  u16* Wk_b = (u16*)alloc((size_t)E_ * E_ * 2);
  u16* Wv_b = (u16*)alloc((size_t)E_ * E_ * 2);
  u16* Wo_b = (u16*)alloc((size_t)E_ * E_ * 2);
  float* bv_f = (float*)alloc(E_ * 4);
  float* bo_f = (float*)alloc(E_ * 4);

  prep_w<<<E_*E_/1024, 256, 0, stream>>>(Wq, Wk, Wv_sh, Wv_sp, Wo_sh, Wo_sp,
                                         bv_sh, bv_sp, bo_sh, bo_sp, lang,
                                         Wq_b, Wk_b, Wv_b, Wo_b, bv_f, bo_f);

  dim3 qkvgrid(512, 3);   // XCD-swizzled 1D work space x matrix select
  gemm_qkv<<<qkvgrid, 256, 0, stream>>>(q, k, v, Wq_b, Wk_b, Wv_b,
                                        bq, bk, bv_f, Qb, Kb, Vt);

  attn_mfma<<<2048, 256, 0, stream>>>(Qb, Kb, Vt, mask, ctxb);

  gemm_lds<<<1024, 256, 0, stream>>>(ctxb, Wo_b, bo_f, (float*)d_out);
}

// Round 5
// 301.788 us; speedup vs baseline: 1.0399x; 1.0005x over previous
//
#include <hip/hip_runtime.h>

#define B_ 16
#define S_ 1024
#define E_ 512
#define H_ 8
#define D_ 64
#define L_ 4
#define M_ (B_*S_)   // 16384 tokens

typedef unsigned short u16;
typedef __attribute__((ext_vector_type(8))) short bf16x8;  // 8 bf16 = 4 VGPRs
typedef __attribute__((ext_vector_type(4))) float f32x4;
typedef __attribute__((ext_vector_type(16))) float f32x16;
typedef __attribute__((ext_vector_type(4))) unsigned uint4v;
typedef __attribute__((ext_vector_type(2))) int int2v;

__device__ __forceinline__ u16 f2bf(float x) {
  unsigned u = __float_as_uint(x);
  unsigned r = (u + 0x7fffu + ((u >> 16) & 1u)) >> 16;  // RNE
  return (u16)r;
}
__device__ __forceinline__ ushort4 f2bf4(float4 f) {
  ushort4 u;
  u.x = f2bf(f.x); u.y = f2bf(f.y); u.z = f2bf(f.z); u.w = f2bf(f.w);
  return u;
}
// single-instruction pack: two f32 -> packed bf16x2 (lo in low half)
__device__ __forceinline__ unsigned cvt_pk_bf16(float lo, float hi) {
  unsigned r;
  asm("v_cvt_pk_bf16_f32 %0, %1, %2" : "=v"(r) : "v"(lo), "v"(hi));
  return r;
}
// permlane32_swap: r[0] = {x.lo, y.lo-moved-to-hi}, r[1] = {x.hi-moved-to-lo, y.hi}
__device__ __forceinline__ int2v plswap(unsigned x, unsigned y) {
  return __builtin_amdgcn_permlane32_swap((int)x, (int)y, false, false);
}

typedef __attribute__((address_space(1))) const void gconst_void;
typedef __attribute__((address_space(3))) void lds_void;
__device__ __forceinline__ void gl_lds16(const void* g, void* l) {
  __builtin_amdgcn_global_load_lds((gconst_void*)g, (lds_void*)l, 16, 0, 0);
}
__device__ __forceinline__ void fence_vm0_barrier() {
  asm volatile("s_waitcnt vmcnt(0)" ::: "memory");
  __builtin_amdgcn_s_barrier();
}

// ---------------- fused weight prep (all 4 weight matrices + biases) ----------------
__global__ __launch_bounds__(256) void prep_w(
    const float* __restrict__ Wq, const float* __restrict__ Wk,
    const float* __restrict__ Wv_sh, const float* __restrict__ Wv_sp,
    const float* __restrict__ Wo_sh, const float* __restrict__ Wo_sp,
    const float* __restrict__ bv_sh, const float* __restrict__ bv_sp,
    const float* __restrict__ bo_sh, const float* __restrict__ bo_sp,
    const int* __restrict__ langp,
    u16* __restrict__ Wq_b, u16* __restrict__ Wk_b,
    u16* __restrict__ Wv_b, u16* __restrict__ Wo_b,
    float* __restrict__ bv_f, float* __restrict__ bo_f) {
  int lang = langp[0];
  int i = blockIdx.x * 256 + threadIdx.x;           // over E_*E_/4
  size_t wofs = (size_t)lang * (E_*E_/4) + i;
  ((ushort4*)Wq_b)[i] = f2bf4(((const float4*)Wq)[i]);
  ((ushort4*)Wk_b)[i] = f2bf4(((const float4*)Wk)[i]);
  float4 vs = ((const float4*)Wv_sh)[i], vp = ((const float4*)Wv_sp)[wofs];
  float4 os = ((const float4*)Wo_sh)[i], op = ((const float4*)Wo_sp)[wofs];
  float4 vv = {vs.x*vp.x, vs.y*vp.y, vs.z*vp.z, vs.w*vp.w};
  float4 oo = {os.x*op.x, os.y*op.y, os.z*op.z, os.w*op.w};
  ((ushort4*)Wv_b)[i] = f2bf4(vv);
  ((ushort4*)Wo_b)[i] = f2bf4(oo);
  if (i < E_/4) {
    float4 b1 = ((const float4*)bv_sh)[i], b2 = ((const float4*)(bv_sp + (size_t)lang*E_))[i];
    float4 b3 = ((const float4*)bo_sh)[i], b4 = ((const float4*)(bo_sp + (size_t)lang*E_))[i];
    float4 r1 = {b1.x+b2.x, b1.y+b2.y, b1.z+b2.z, b1.w+b2.w};
    float4 r2 = {b3.x+b4.x, b3.y+b4.y, b3.z+b4.z, b3.w+b4.w};
    ((float4*)bv_f)[i] = r1;
    ((float4*)bo_f)[i] = r2;
  }
}

// ---------------- fused QKV projection GEMM: {Q,K,V}b = {q,k,v} @ W^T + b ----------------
// (unchanged from R4) 128x128 tile, BK=32, dbuf, reg-staged A with swizzle,
// gload_lds B with inverse-swizzled source. z==2 writes transposed Vt.
#define ABBUF 8192   // bytes per LDS buffer (128 rows x 64B)
__global__ __launch_bounds__(256, 4) void gemm_qkv(
    const float* __restrict__ q, const float* __restrict__ k, const float* __restrict__ v,
    const u16* __restrict__ Wq_b, const u16* __restrict__ Wk_b, const u16* __restrict__ Wv_b,
    const float* __restrict__ bq, const float* __restrict__ bk, const float* __restrict__ bv,
    u16* __restrict__ Qb, u16* __restrict__ Kb, u16* __restrict__ Vt) {
  __shared__ __align__(16) u16 sA[2*4096];   // 16KB (bf16 A, dbuf)
  __shared__ __align__(16) u16 sB[2*4096];   // 16KB
  const int z = blockIdx.y;
  const float* A    = (z == 0) ? q : (z == 1) ? k : v;
  const u16*   Bw   = (z == 0) ? Wq_b : (z == 1) ? Wk_b : Wv_b;
  const float* bias = (z == 0) ? bq : (z == 1) ? bk : bv;
  const int t = threadIdx.x;
  const int hw = blockIdx.x;
  const int wk = (hw & 7) * 64 + (hw >> 3);
  const int m0 = (wk >> 2) * 128, n0 = (wk & 3) * 128;
  const int lane = t & 63, wid = t >> 6;
  const int m16 = lane & 15, qq = lane >> 4;
  const int wrow = (wid >> 1) * 64, wcol = (wid & 1) * 64;
  const int key = (lane & 7) << 4;
  f32x4 acc[4][4] = {};
  const int arow = t >> 1;
  const float* aR = A + (size_t)(m0 + arow) * E_ + (t & 1) * 16;
  const int awr0 = (arow*64 + (t&1)*32)      ^ ((arow & 7) << 4);
  const int awr1 = (arow*64 + (t&1)*32 + 16) ^ ((arow & 7) << 4);
  const int cb0 = wid*2, cb1 = wid*2 + 1;
  const int rl0 = ((lane>>2)&1) ^ ((lane>>4)&1);
  const int brow = 2*(lane>>3) + rl0;
  const int bcol = (((lane&1)^rl0)<<3) + ((((lane>>1)&1) ^ ((lane>>3)&1))<<4);
  const u16* bp0 = Bw + (size_t)(n0 + cb0*16 + brow) * E_ + bcol;
  const u16* bp1 = Bw + (size_t)(n0 + cb1*16 + brow) * E_ + bcol;
  char* sAb = (char*)sA;
  char* sBb = (char*)sB;
  gl_lds16(bp0, sBb + cb0*1024);
  gl_lds16(bp1, sBb + cb1*1024);
  f32x4 ar0 = *(const f32x4*)aR;
  f32x4 ar1 = *(const f32x4*)(aR + 4);
  f32x4 ar2 = *(const f32x4*)(aR + 8);
  f32x4 ar3 = *(const f32x4*)(aR + 12);
  aR += 32; bp0 += 32; bp1 += 32;
  asm volatile("s_waitcnt vmcnt(0)" ::: "memory");
  {
    uint4v w0 = { cvt_pk_bf16(ar0[0],ar0[1]), cvt_pk_bf16(ar0[2],ar0[3]),
                  cvt_pk_bf16(ar1[0],ar1[1]), cvt_pk_bf16(ar1[2],ar1[3]) };
    uint4v w1 = { cvt_pk_bf16(ar2[0],ar2[1]), cvt_pk_bf16(ar2[2],ar2[3]),
                  cvt_pk_bf16(ar3[0],ar3[1]), cvt_pk_bf16(ar3[2],ar3[3]) };
    *(uint4v*)(sAb + awr0) = w0;
    *(uint4v*)(sAb + awr1) = w1;
  }
  asm volatile("s_waitcnt lgkmcnt(0)" ::: "memory");
  __builtin_amdgcn_s_barrier();
  for (int kt = 0; kt < 16; ++kt) {
    const int cur = (kt & 1) * ABBUF;
    const int nxt = ABBUF - cur;
    if (kt < 15) {
      gl_lds16(bp0, sBb + nxt + cb0*1024);
      gl_lds16(bp1, sBb + nxt + cb1*1024);
      ar0 = *(const f32x4*)aR;
      ar1 = *(const f32x4*)(aR + 4);
      ar2 = *(const f32x4*)(aR + 8);
      ar3 = *(const f32x4*)(aR + 12);
      aR += 32; bp0 += 32; bp1 += 32;
    }
    bf16x8 af[4], bfm[4];
#pragma unroll
    for (int mt = 0; mt < 4; ++mt) {
      int row = wrow + mt*16 + m16;
      af[mt] = *(const bf16x8*)(sAb + cur + ((row*64 + qq*16) ^ key));
    }
#pragma unroll
    for (int nt = 0; nt < 4; ++nt) {
      int row = wcol + nt*16 + m16;
      bfm[nt] = *(const bf16x8*)(sBb + cur + ((row*64 + qq*16) ^ key));
    }
#pragma unroll
    for (int mt = 0; mt < 4; ++mt)
#pragma unroll
      for (int nt = 0; nt < 4; ++nt)
        acc[mt][nt] = __builtin_amdgcn_mfma_f32_16x16x32_bf16(af[mt], bfm[nt], acc[mt][nt], 0, 0, 0);
    if (kt < 15) {
      asm volatile("s_waitcnt vmcnt(0)" ::: "memory");
      uint4v w0 = { cvt_pk_bf16(ar0[0],ar0[1]), cvt_pk_bf16(ar0[2],ar0[3]),
                    cvt_pk_bf16(ar1[0],ar1[1]), cvt_pk_bf16(ar1[2],ar1[3]) };
      uint4v w1 = { cvt_pk_bf16(ar2[0],ar2[1]), cvt_pk_bf16(ar2[2],ar2[3]),
                    cvt_pk_bf16(ar3[0],ar3[1]), cvt_pk_bf16(ar3[2],ar3[3]) };
      *(uint4v*)(sAb + nxt + awr0) = w0;
      *(uint4v*)(sAb + nxt + awr1) = w1;
      asm volatile("s_waitcnt lgkmcnt(0)" ::: "memory");
      __builtin_amdgcn_s_barrier();
    }
  }
  float bvv[4];
#pragma unroll
  for (int nt = 0; nt < 4; ++nt) bvv[nt] = bias[n0 + wcol + nt*16 + m16];
  if (z < 2) {
    u16* out = (z == 0) ? Qb : Kb;
#pragma unroll
    for (int mt = 0; mt < 4; ++mt) {
      int gm = m0 + wrow + mt*16 + qq*4;
#pragma unroll
      for (int nt = 0; nt < 4; ++nt) {
        int gn = n0 + wcol + nt*16 + m16;
#pragma unroll
        for (int r = 0; r < 4; ++r)
          out[(size_t)(gm + r) * E_ + gn] = f2bf(acc[mt][nt][r] + bvv[nt]);
      }
    }
  } else {
#pragma unroll
    for (int mt = 0; mt < 4; ++mt) {
      int tok0 = m0 + wrow + mt*16 + qq*4;
      int bb = tok0 >> 10, s0 = tok0 & 1023;
#pragma unroll
      for (int nt = 0; nt < 4; ++nt) {
        int dim = n0 + wcol + nt*16 + m16;
        uint2 wv = { cvt_pk_bf16(acc[mt][nt][0] + bvv[nt], acc[mt][nt][1] + bvv[nt]),
                     cvt_pk_bf16(acc[mt][nt][2] + bvv[nt], acc[mt][nt][3] + bvv[nt]) };
        *(uint2*)(Vt + ((size_t)(bb*E_ + dim))*S_ + s0) = wv;
      }
    }
  }
}

// ---------------- bf16 MFMA GEMM, 128x64 tile (unchanged from R4) ----------------
__global__ __launch_bounds__(256, 4) void gemm_lds(
    const u16* __restrict__ A, const u16* __restrict__ Bw,
    const float* __restrict__ bias, float* __restrict__ out) {
  __shared__ __align__(16) u16 sAD[2*4096];
  __shared__ __align__(16) u16 sBD[2*2048];
  const int t = threadIdx.x;
  const int hw = blockIdx.x;
  const int wk = (hw & 7) * 128 + (hw >> 3);
  const int m0 = (wk >> 3) * 128, n0 = (wk & 7) * 64;
  const int lane = t & 63, wid = t >> 6;
  const int m16 = lane & 15, qq = lane >> 4;
  const int wrow = (wid >> 1) * 64, wcol = (wid & 1) * 32;
  const int key = (lane & 7) << 4;
  f32x4 acc[4][2] = {};
  const int rl0 = ((lane>>2)&1) ^ ((lane>>4)&1);
  const int brow = 2*(lane>>3) + rl0;
  const int bcol = (((lane&1)^rl0)<<3) + ((((lane>>1)&1) ^ ((lane>>3)&1))<<4);
  const int c0 = 2*wid, c1 = 2*wid + 1;
  const u16* a0 = A  + (size_t)(m0 + c0*16 + brow) * E_ + bcol;
  const u16* a1 = A  + (size_t)(m0 + c1*16 + brow) * E_ + bcol;
  const u16* b0 = Bw + (size_t)(n0 + wid*16 + brow) * E_ + bcol;
  char* sAb = (char*)sAD;
  char* sBb = (char*)sBD;
  gl_lds16(a0, sAb + c0*1024);
  gl_lds16(a1, sAb + c1*1024);
  gl_lds16(b0, sBb + wid*1024);
  a0 += 32; a1 += 32; b0 += 32;
  fence_vm0_barrier();
  for (int kt = 0; kt < 16; ++kt) {
    const int curA = (kt & 1) * 8192, nxtA = 8192 - curA;
    const int curB = (kt & 1) * 4096, nxtB = 4096 - curB;
    if (kt < 15) {
      gl_lds16(a0, sAb + nxtA + c0*1024);
      gl_lds16(a1, sAb + nxtA + c1*1024);
      gl_lds16(b0, sBb + nxtB + wid*1024);
      a0 += 32; a1 += 32; b0 += 32;
    }
    bf16x8 af[4], bfm[2];
#pragma unroll
    for (int mt = 0; mt < 4; ++mt) {
      int row = wrow + mt*16 + m16;
      af[mt] = *(const bf16x8*)(sAb + curA + ((row*64 + qq*16) ^ key));
    }
#pragma unroll
    for (int nt = 0; nt < 2; ++nt) {
      int row = wcol + nt*16 + m16;
      bfm[nt] = *(const bf16x8*)(sBb + curB + ((row*64 + qq*16) ^ key));
    }
#pragma unroll
    for (int mt = 0; mt < 4; ++mt)
#pragma unroll
      for (int nt = 0; nt < 2; ++nt)
        acc[mt][nt] = __builtin_amdgcn_mfma_f32_16x16x32_bf16(af[mt], bfm[nt], acc[mt][nt], 0, 0, 0);
    if (kt < 15) fence_vm0_barrier();
  }
  float bv[2];
#pragma unroll
  for (int nt = 0; nt < 2; ++nt) bv[nt] = bias[n0 + wcol + nt*16 + m16];
#pragma unroll
  for (int mt = 0; mt < 4; ++mt) {
    int gm = m0 + wrow + mt*16 + qq*4;
#pragma unroll
    for (int nt = 0; nt < 2; ++nt) {
      int gn = n0 + wcol + nt*16 + m16;
#pragma unroll
      for (int r = 0; r < 4; ++r)
        out[(size_t)(gm + r) * E_ + gn] = acc[mt][nt][r] + bv[nt];
    }
  }
}

// ---------------- MFMA flash attention v2: 32x32 MFMA, in-register P ----------------
// Block = (b,h, 128 q-rows); 4 waves, wave w owns q-rows [w*32, w*32+32).
// S^T = mfma_32x32x16(K, Q): C/D col=lane&31=qrow, row=key=(reg&3)+8*(reg>>2)+4*(lane>>5).
// -> each lane holds 16 keys of ONE q-row -> softmax fully in-register; P redistributed
// to PV A-operand layout via cvt_pk + permlane32_swap (T12) -- zero P LDS traffic.
// l-reduce: single shfl_xor(32). 2x FLOP per LDS byte vs 16x16 version.
#define KST 72   // padded LDS row stride (u16): 144B rows -> 2-way bank aliasing (free)
__global__ __launch_bounds__(256) void attn_mfma(
    const u16* __restrict__ Qb, const u16* __restrict__ Kb, const u16* __restrict__ Vt,
    const int* __restrict__ mask, u16* __restrict__ ctxb) {
  __shared__ __align__(16) u16 sKV[2*64*KST];   // sK | sV^T ; epilogue: O staging (128x72)
  __shared__ __align__(16) float sMask[64];
  __shared__ __align__(16) float sL[128];
  u16* sK = sKV;
  u16* sV = sKV + 64*KST;
  const int t = threadIdx.x;
  const int lane = t & 63, w = t >> 6;
  const int l31 = lane & 31, lh = lane >> 5;
  // XCD swizzle: 1024 blocks, 8 XCDs, 128/chunk -> 16 bh (4MB K/V) per XCD
  const int hw = blockIdx.x;
  const int wk = (hw & 7) * 128 + (hw >> 3);
  const int bh = wk >> 3, b = bh >> 3, h = bh & 7;
  const int qblk = (wk & 7) * 128;
  const int q0 = qblk + w * 32;
  // Q as B-operand: col=lane&31=qrow, k=(lane>>5)*8+j; 4 k-steps over D=64
  bf16x8 qfr[4];
  {
    const u16* qp = Qb + (size_t)(b*S_ + q0 + l31) * E_ + h*D_ + lh*8;
#pragma unroll
    for (int s = 0; s < 4; ++s) qfr[s] = *(const bf16x8*)(qp + s*16);
  }
  f32x16 oacc[2] = {};   // [nt]: dims nt*32+l31; rows (reg&3)+8*(reg>>2)+4*lh
  float lpart = 0.f;
  const int srow = t >> 2, sc0 = (t & 3) * 16;
  const u16* kp = Kb + (size_t)(b*S_ + srow) * E_ + h*D_ + sc0;
  const u16* vp = Vt + ((size_t)(b*H_ + h) * D_ + srow) * S_ + sc0;
  uint4 rk0 = *(const uint4*)kp, rk1 = *(const uint4*)(kp + 8);
  uint4 rv0 = *(const uint4*)vp, rv1 = *(const uint4*)(vp + 8);
  float rmsk = 0.f;
  if (t < 64) rmsk = (mask[b*S_ + t] == 0) ? -1e9f : 0.f;
  const float CS = 0.015625f * 1.44269504f;   // (1/64)*log2(e)
  for (int kt = 0; kt < S_; kt += 64) {
    *(uint4*)&sK[srow*KST + sc0]     = rk0;
    *(uint4*)&sK[srow*KST + sc0 + 8] = rk1;
    *(uint4*)&sV[srow*KST + sc0]     = rv0;
    *(uint4*)&sV[srow*KST + sc0 + 8] = rv1;
    if (t < 64) sMask[t] = rmsk;
    __syncthreads();
    if (kt + 64 < S_) {   // prefetch next tile into regs (hidden under compute)
      kp += (size_t)64 * E_; vp += 64;
      rk0 = *(const uint4*)kp; rk1 = *(const uint4*)(kp + 8);
      rv0 = *(const uint4*)vp; rv1 = *(const uint4*)(vp + 8);
      if (t < 64) rmsk = (mask[b*S_ + kt + 64 + t] == 0) ? -1e9f : 0.f;
    }
    // ---- S^T = K Q^T : A=K (m=key 64 = 2 tiles), B=Q (n=qrow 32); 4 k-steps ----
    f32x16 sacc[2] = {};
#pragma unroll
    for (int mt = 0; mt < 2; ++mt)
#pragma unroll
      for (int s = 0; s < 4; ++s) {
        bf16x8 kf = *(const bf16x8*)&sK[(mt*32 + l31)*KST + s*16 + lh*8];
        sacc[mt] = __builtin_amdgcn_mfma_f32_32x32x16_bf16(kf, qfr[s], sacc[mt], 0, 0, 0);
      }
    // ---- softmax in-register: lane holds keys mt*32 + 8g + 4lh + r2 for qrow l31 ----
    unsigned pw[2][4][2];   // [mt][g][h]: bf16 pair, keys mt*32+8g+4lh+{2h,2h+1}
#pragma unroll
    for (int mt = 0; mt < 2; ++mt)
#pragma unroll
      for (int g = 0; g < 4; ++g) {
        f32x4 msk = *(const f32x4*)&sMask[mt*32 + g*8 + lh*4];   // broadcast read
        float p0 = exp2f(fmaf(sacc[mt][4*g+0], CS, msk[0]));
        float p1 = exp2f(fmaf(sacc[mt][4*g+1], CS, msk[1]));
        float p2 = exp2f(fmaf(sacc[mt][4*g+2], CS, msk[2]));
        float p3 = exp2f(fmaf(sacc[mt][4*g+3], CS, msk[3]));
        lpart += (p0 + p1) + (p2 + p3);
        pw[mt][g][0] = cvt_pk_bf16(p0, p1);
        pw[mt][g][1] = cvt_pk_bf16(p2, p3);
      }
    // ---- O += P V : A=P (in-reg via permlane), B=V^T; 2 n-tiles x 4 k-steps ----
#pragma unroll
    for (int s = 0; s < 4; ++s) {
      const int mt = s >> 1, c = s & 1;
      int2v P1 = plswap(pw[mt][2*c][0], pw[mt][2*c+1][0]);
      int2v P2 = plswap(pw[mt][2*c][1], pw[mt][2*c+1][1]);
      union { uint4v u; bf16x8 h8; } pa;
      pa.u = (uint4v){ (unsigned)P1[0], (unsigned)P2[0], (unsigned)P1[1], (unsigned)P2[1] };
#pragma unroll
      for (int nt = 0; nt < 2; ++nt) {
        bf16x8 vf = *(const bf16x8*)&sV[(nt*32 + l31)*KST + s*16 + lh*8];
        oacc[nt] = __builtin_amdgcn_mfma_f32_32x32x16_bf16(pa.h8, vf, oacc[nt], 0, 0, 0);
      }
    }
    __syncthreads();   // all waves done reading sK/sV before next staging
  }
  // ---- l: lane's lpart covers half the keys of qrow=l31; other half in lane^32 ----
  lpart += __shfl_xor(lpart, 32);
  if (lane < 32) sL[w*32 + l31] = lpart;
  // oacc rows = 8g+4lh+r2 -> need l per row: f32x4 at sL[w*32+8g+4lh]
  f32x4 linv[4];
#pragma unroll
  for (int g = 0; g < 4; ++g) {
    f32x4 lv = *(const f32x4*)&sL[w*32 + 8*g + 4*lh];
    linv[g] = (f32x4){1.0f/lv[0], 1.0f/lv[1], 1.0f/lv[2], 1.0f/lv[3]};
  }
  // ---- epilogue: normalize, stage in sKV (re-used as 128x72 O buffer), store ----
#pragma unroll
  for (int nt = 0; nt < 2; ++nt)
#pragma unroll
    for (int g = 0; g < 4; ++g)
#pragma unroll
      for (int r2 = 0; r2 < 4; ++r2) {
        int qoff = 8*g + 4*lh + r2;
        sKV[(w*32 + qoff)*KST + nt*32 + l31] = f2bf(oacc[nt][4*g+r2] * linv[g][r2]);
      }
  __syncthreads();
  const int row = t >> 1, c0 = (t & 1) * 32;
  uint4 o0 = *(uint4*)&sKV[row*KST + c0];
  uint4 o1 = *(uint4*)&sKV[row*KST + c0 + 8];
  uint4 o2 = *(uint4*)&sKV[row*KST + c0 + 16];
  uint4 o3 = *(uint4*)&sKV[row*KST + c0 + 24];
  u16* dst = ctxb + (size_t)(b*S_ + qblk + row) * E_ + h*D_ + c0;
  *(uint4*)dst = o0;
  *(uint4*)(dst + 8)  = o1;
  *(uint4*)(dst + 16) = o2;
  *(uint4*)(dst + 24) = o3;
}

// ---------------- launch ----------------
extern "C" void kernel_launch(void* const* d_in, const int* in_sizes, int n_in,
                              void* d_out, int out_size, void* d_ws, size_t ws_size,
                              hipStream_t stream) {
  const float* q     = (const float*)d_in[0];
  const float* k     = (const float*)d_in[1];
  const float* v     = (const float*)d_in[2];
  const float* Wq    = (const float*)d_in[3];
  const float* bq    = (const float*)d_in[4];
  const float* Wk    = (const float*)d_in[5];
  const float* bk    = (const float*)d_in[6];
  const float* Wv_sh = (const float*)d_in[7];
  const float* Wv_sp = (const float*)d_in[8];
  const float* bv_sh = (const float*)d_in[9];
  const float* bv_sp = (const float*)d_in[10];
  const float* Wo_sh = (const float*)d_in[11];
  const float* Wo_sp = (const float*)d_in[12];
  const float* bo_sh = (const float*)d_in[13];
  const float* bo_sp = (const float*)d_in[14];
  const int*   mask  = (const int*)d_in[15];
  const int*   lang  = (const int*)d_in[16];

  char* ws = (char*)d_ws;
  size_t off = 0;
  auto alloc = [&](size_t bytes) -> char* {
    char* p = ws + off;
    off += (bytes + 255) & ~(size_t)255;
    return p;
  };
  u16* Qb   = (u16*)alloc((size_t)M_ * E_ * 2);
  u16* Kb   = (u16*)alloc((size_t)M_ * E_ * 2);
  u16* Vt   = (u16*)alloc((size_t)M_ * E_ * 2);
  u16* ctxb = (u16*)alloc((size_t)M_ * E_ * 2);
  u16* Wq_b = (u16*)alloc((size_t)E_ * E_ * 2);
  u16* Wk_b = (u16*)alloc((size_t)E_ * E_ * 2);
  u16* Wv_b = (u16*)alloc((size_t)E_ * E_ * 2);
  u16* Wo_b = (u16*)alloc((size_t)E_ * E_ * 2);
  float* bv_f = (float*)alloc(E_ * 4);
  float* bo_f = (float*)alloc(E_ * 4);

  prep_w<<<E_*E_/1024, 256, 0, stream>>>(Wq, Wk, Wv_sh, Wv_sp, Wo_sh, Wo_sp,
                                         bv_sh, bv_sp, bo_sh, bo_sp, lang,
                                         Wq_b, Wk_b, Wv_b, Wo_b, bv_f, bo_f);

  dim3 qkvgrid(512, 3);
  gemm_qkv<<<qkvgrid, 256, 0, stream>>>(q, k, v, Wq_b, Wk_b, Wv_b,
                                        bq, bk, bv_f, Qb, Kb, Vt);

  attn_mfma<<<1024, 256, 0, stream>>>(Qb, Kb, Vt, mask, ctxb);

  gemm_lds<<<1024, 256, 0, stream>>>(ctxb, Wo_b, bo_f, (float*)d_out);
}